// Round 10
// baseline (816.069 us; speedup 1.0000x reference)
//
#include <hip/hip_runtime.h>
#include <cstdint>
#include <cstddef>

// ---------------------------------------------------------------------------
// SiglipAttention fake-quant.  B=16 S=729 E=1152 H=16 D=72.
// Outputs fp32: attn_output (B,S,E) then attn_weights (B,H,S,S).
// Round 10: XCD-locality swizzle (same-bh blocks -> same XCD) for qk_statsA
//           and qk_pv; V frags loaded before P-store phase.  Rest identical.
// ---------------------------------------------------------------------------

typedef unsigned short ushort_t;

constexpr int   cB = 16, cS = 729, cE = 1152, cH = 16, cD = 72;
constexpr int   cM = cB * cS;                    // 11664
constexpr long  cQKV  = (long)cM * cE;           // 13,436,928
constexpr long  cWN   = (long)cE * cE;           // 1,327,104
constexpr float cScale = 0.11785113019775792f;   // 72^-0.5
constexpr int   cSP = 768;                       // padded S rows for qb/kb
constexpr int   cDP96 = 96;                      // padded D for MFMA K
constexpr int   cVD = 80;                        // vT d-rows (72 used + 8 pad)
constexpr int   cMF = 11776;                     // padded M (92 tiles of 128)
constexpr int   cRB = 2304;                      // i8 row bytes: [h 1152 | l 1152]

// ---- workspace byte offsets (total ~147 MB <= proven 243.7 MB) -------------
constexpr size_t B_SCAL = 0;                                    // 16 f32
constexpr size_t SZ_W2  = (size_t)cE * cRB;                     // 2,654,208
constexpr size_t B_W2O  = 256;
constexpr size_t B_W2Q  = B_W2O + SZ_W2;                        // W2Q,K,V contiguous
constexpr size_t B_A2   = B_W2Q + 3 * SZ_W2;
constexpr size_t SZ_A2  = (size_t)cMF * cRB;                    // 27,131,904
constexpr size_t B_VT   = B_A2 + SZ_A2;
constexpr size_t SZ_VT  = (size_t)256 * cVD * cSP * 2;          // 31,457,280
constexpr size_t B_QB   = B_VT + SZ_VT;
constexpr size_t SZ_QB  = (size_t)256 * cSP * cDP96 * 2;        // 37,748,736
constexpr size_t B_KB   = B_QB + SZ_QB;
constexpr size_t B_ROWM = B_KB + SZ_QB;
constexpr size_t SZ_ROW = (size_t)256 * cS * 4;                 // 746,496
constexpr size_t B_ROWZ = B_ROWM + SZ_ROW;
constexpr size_t WS_TOTAL = B_ROWZ + SZ_ROW;
static_assert(WS_TOTAL <= 243689728, "stay under proven ws size");

// scalar slots: 0 hid,1 wq,2 wk,3 wv,4 wo,5 q,6 k,7 v,8 minZ,9 attn

typedef __attribute__((ext_vector_type(8))) short bf16x8;
typedef __attribute__((ext_vector_type(4))) float f32x4;
typedef __attribute__((ext_vector_type(4))) int   i32x4;
#define MFMA16 __builtin_amdgcn_mfma_f32_16x16x32_bf16
#define MFMAI8 __builtin_amdgcn_mfma_i32_16x16x64_i8

__device__ __forceinline__ unsigned short f2bf(float f) {
  unsigned u = __float_as_uint(f);
  return (unsigned short)((u + 0x7fffu + ((u >> 16) & 1u)) >> 16);   // RNE
}
__device__ __forceinline__ float bf2f(unsigned short h) {
  return __uint_as_float(((unsigned)h) << 16);
}
__device__ __forceinline__ void gload16(const void* g, void* l) {
  __builtin_amdgcn_global_load_lds((const __attribute__((address_space(1))) unsigned int*)g,
                                   (__attribute__((address_space(3))) unsigned int*)l, 16, 0, 0);
}

// ---------------------------------------------------------------------------
__global__ void init_k(float* sc) {
  int t = threadIdx.x;
  if (t < 16) sc[t] = (t == 8) ? __uint_as_float(0x7f800000u) : 0.0f;
}

// consolidated absmax over 5 tensors: blockIdx.y selects tensor -> scal[y]
__global__ __launch_bounds__(256) void absmax5_k(const float4* __restrict__ x0, const float4* __restrict__ x1,
                                                 const float4* __restrict__ x2, const float4* __restrict__ x3,
                                                 const float4* __restrict__ x4, unsigned int* __restrict__ scal) {
  int t = blockIdx.y;
  const float4* x = (t == 0) ? x0 : (t == 1) ? x1 : (t == 2) ? x2 : (t == 3) ? x3 : x4;
  long n4 = (t == 0) ? cQKV / 4 : cWN / 4;
  float m = 0.f;
  long i = (long)blockIdx.x * blockDim.x + threadIdx.x;
  long str = (long)gridDim.x * blockDim.x;
  for (; i < n4; i += str) {
    float4 v = x[i];
    m = fmaxf(m, fmaxf(fmaxf(fabsf(v.x), fabsf(v.y)), fmaxf(fabsf(v.z), fabsf(v.w))));
  }
  for (int o = 32; o; o >>= 1) m = fmaxf(m, __shfl_xor(m, o));
  __shared__ float red[4];
  int lane = threadIdx.x & 63, w = threadIdx.x >> 6;
  if (!lane) red[w] = m;
  __syncthreads();
  if (threadIdx.x == 0) {
    m = fmaxf(fmaxf(red[0], red[1]), fmaxf(red[2], red[3]));
    atomicMax(&scal[t], __float_as_uint(m));
  }
}

// ---------------------------------------------------------------------------
// fq16 -> integer n -> hi/lo i8 planes: n = 256*a + b (exact except clamp tail)
__global__ __launch_bounds__(256) void pack8_k(const float* __restrict__ src, const float* __restrict__ slot,
                                               char* __restrict__ dst, int nsrc) {
  float s = fmaxf(*slot, 1e-8f) / 32767.f;
  int i = blockIdx.x * 256 + threadIdx.x;
  int r = i / 72, c16 = i - r * 72;
  int m = (r < nsrc) ? r : nsrc - 1;
  const float4* p = (const float4*)(src + (long)m * cE + c16 * 16);
  float4 v[4] = {p[0], p[1], p[2], p[3]};
  const float* xv = (const float*)v;
  unsigned char hb[16] __attribute__((aligned(16)));
  unsigned char lb[16] __attribute__((aligned(16)));
#pragma unroll
  for (int j = 0; j < 16; ++j) {
    float t = rintf(xv[j] / s);
    t = fminf(fmaxf(t, -32767.f), 32767.f);
    float af = floorf(t * 0.00390625f + 0.5f);   // round-half-up to hi byte
    af = fminf(af, 127.f);
    float bf = t - 256.f * af;
    bf = fminf(fmaxf(bf, -128.f), 127.f);
    hb[j] = (unsigned char)((int)af & 0xff);
    lb[j] = (unsigned char)((int)bf & 0xff);
  }
  char* d = dst + (long)r * cRB + c16 * 16;
  *(uint4*)d = *(const uint4*)hb;
  *(uint4*)(d + 1152) = *(const uint4*)lb;
}

// consolidated weight pack: blockIdx.y = z (0 wq,1 wk,2 wv,3 wo)
__global__ __launch_bounds__(256) void packW4_k(const float* __restrict__ w0, const float* __restrict__ w1,
                                                const float* __restrict__ w2, const float* __restrict__ w3,
                                                const float* __restrict__ scal,
                                                char* __restrict__ W2Q, char* __restrict__ W2O) {
  int z = blockIdx.y;
  const float* src = (z == 0) ? w0 : (z == 1) ? w1 : (z == 2) ? w2 : w3;
  char* dst = (z < 3) ? (W2Q + (size_t)z * SZ_W2) : W2O;
  float s = fmaxf(scal[1 + z], 1e-8f) / 32767.f;
  int i = blockIdx.x * 256 + threadIdx.x;
  int r = i / 72, c16 = i - r * 72;
  const float4* p = (const float4*)(src + (long)r * cE + c16 * 16);
  float4 v[4] = {p[0], p[1], p[2], p[3]};
  const float* xv = (const float*)v;
  unsigned char hb[16] __attribute__((aligned(16)));
  unsigned char lb[16] __attribute__((aligned(16)));
#pragma unroll
  for (int j = 0; j < 16; ++j) {
    float t = rintf(xv[j] / s);
    t = fminf(fmaxf(t, -32767.f), 32767.f);
    float af = floorf(t * 0.00390625f + 0.5f);
    af = fminf(af, 127.f);
    float bf = t - 256.f * af;
    bf = fminf(fmaxf(bf, -128.f), 127.f);
    hb[j] = (unsigned char)((int)af & 0xff);
    lb[j] = (unsigned char)((int)bf & 0xff);
  }
  char* d = dst + (long)r * cRB + c16 * 16;
  *(uint4*)d = *(const uint4*)hb;
  *(uint4*)(d + 1152) = *(const uint4*)lb;
}

// ---------------------------------------------------------------------------
// int8 MFMA GEMM (unchanged, verified).
template <int OM>
__global__ __launch_bounds__(256, 2) void mgemm_k(const char* __restrict__ A2,
                                                  const char* __restrict__ W2base,
                                                  const float* __restrict__ b0, const float* __restrict__ b1,
                                                  const float* __restrict__ b2,
                                                  float* __restrict__ outbase, float* __restrict__ scal) {
  __shared__ char L[2][32768];
  int z = (OM == 0) ? blockIdx.z : 0;
  const char* W2 = W2base + (size_t)z * cE * cRB;
  const float* bias = (z == 0) ? b0 : (z == 1) ? b1 : b2;
  float* out = outbase + (long)z * cQKV;
  float sA = fmaxf(scal[OM == 0 ? 0 : 9], 1e-8f) / 32767.f;
  float sW = fmaxf(scal[OM == 0 ? 1 + z : 4], 1e-8f) / 32767.f;
  float sc = sA * sW;

  int tid = threadIdx.x, w = tid >> 6, lane = tid & 63;
  int lr = lane & 15, kc = lane >> 4;
  int mt = blockIdx.y * 128, nt = blockIdx.x * 128;
  int wr = (w >> 1) * 64, wc = (w & 1) * 64;

  bool isA = (w < 2);
  const char* mat = isA ? (A2 + (long)mt * cRB) : (W2 + (long)nt * cRB);
  const char* src[8];
  int ldo[8];
#pragma unroll
  for (int j = 0; j < 8; ++j) {
    int seg = (w & 1) * 8 + j;
    int o = seg * 1024 + lane * 16;
    int row = o >> 7, chs = (o >> 4) & 7, orig = chs ^ (row & 7);
    src[j] = mat + (long)row * cRB + (orig >> 2) * 1152 + (orig & 3) * 16;
    ldo[j] = (isA ? 0 : 16384) + seg * 1024;
  }

  int aoffH[4], aoffL[4], boffH[4], boffL[4];
#pragma unroll
  for (int i = 0; i < 4; ++i) {
    int ra = wr + i * 16 + lr;
    aoffH[i] = ra * 128 + ((kc ^ (ra & 7)) << 4);
    aoffL[i] = ra * 128 + (((kc + 4) ^ (ra & 7)) << 4);
    int rb = wc + i * 16 + lr;
    boffH[i] = 16384 + rb * 128 + ((kc ^ (rb & 7)) << 4);
    boffL[i] = 16384 + rb * 128 + (((kc + 4) ^ (rb & 7)) << 4);
  }

  auto stage = [&](int buf, int kk) {
#pragma unroll
    for (int j = 0; j < 8; ++j)
      gload16(src[j] + (long)kk * 64, &L[buf][ldo[j]]);
  };

  i32x4 P1[4][4] = {};
  i32x4 Pm[4][4] = {};
  stage(0, 0);
  __syncthreads();
  int cur = 0;
  for (int kk = 0; kk < 18; ++kk) {
    if (kk < 17) stage(cur ^ 1, kk + 1);
    i32x4 ah[4], al[4], whf[4], wlf[4];
#pragma unroll
    for (int i = 0; i < 4; ++i) {
      ah[i]  = *(const i32x4*)&L[cur][aoffH[i]];
      al[i]  = *(const i32x4*)&L[cur][aoffL[i]];
      whf[i] = *(const i32x4*)&L[cur][boffH[i]];
      wlf[i] = *(const i32x4*)&L[cur][boffL[i]];
    }
#pragma unroll
    for (int i = 0; i < 4; ++i)
#pragma unroll
      for (int j = 0; j < 4; ++j) {
        P1[i][j] = MFMAI8(ah[i], whf[j], P1[i][j], 0, 0, 0);
        Pm[i][j] = MFMAI8(ah[i], wlf[j], Pm[i][j], 0, 0, 0);
        Pm[i][j] = MFMAI8(al[i], whf[j], Pm[i][j], 0, 0, 0);
      }
    __syncthreads();
    cur ^= 1;
  }

  float amx = 0.f;
#pragma unroll
  for (int i = 0; i < 4; ++i) {
#pragma unroll
    for (int r = 0; r < 4; ++r) {
      int m = mt + wr + i * 16 + kc * 4 + r;
      if (m >= cM) continue;
      int b = m / cS, s = m - b * cS;
#pragma unroll
      for (int j = 0; j < 4; ++j) {
        int n = nt + wc + j * 16 + lr;
        float val = 65536.f * (float)P1[i][j][r] + 256.f * (float)Pm[i][j][r];
        float cv = sc * val + bias[n];
        if (OM == 1) {
          out[(long)m * cE + n] = cv;
        } else {
          int h = n / cD, d = n - h * cD;
          out[((long)(b * cH + h) * cS + s) * cD + d] = cv;
          amx = fmaxf(amx, fabsf(cv));
        }
      }
    }
  }
  if (OM == 0) {
    for (int o = 32; o; o >>= 1) amx = fmaxf(amx, __shfl_xor(amx, o));
    if (lane == 0) atomicMax((unsigned int*)(scal + 5 + z), __float_as_uint(amx));
  }
}

// ---------------------------------------------------------------------------
// q/k fp32 (bh,729,72) -> 8-bit integer as bf16 (bh,768,96); blockIdx.y = q/k
__global__ __launch_bounds__(256) void qk82_k(const float* __restrict__ Rq, const float* __restrict__ Rk,
                                              ushort_t* __restrict__ qb, ushort_t* __restrict__ kb,
                                              const float* __restrict__ scal) {
  int z = blockIdx.y;
  const float* src = z ? Rk : Rq;
  ushort_t* dst = z ? kb : qb;
  float s8 = fmaxf(scal[5 + z], 1e-8f) / 127.f;
  long total2 = (long)256 * cSP * cDP96 / 2;
  long i = (long)blockIdx.x * blockDim.x + threadIdx.x;
  long str = (long)gridDim.x * blockDim.x;
  for (; i < total2; i += str) {
    long e = i * 2;
    int d = (int)(e % cDP96);
    long rem = e / cDP96;
    int s = (int)(rem % cSP);
    int bh = (int)(rem / cSP);
    float v0 = 0.f, v1 = 0.f;
    if (s < cS && d < cD) {
      const float* p = src + ((long)bh * cS + s) * cD + d;
      v0 = p[0]; v1 = p[1];
    }
    float n0 = fminf(fmaxf(rintf(v0 / s8), -127.f), 127.f);
    float n1 = fminf(fmaxf(rintf(v1 / s8), -127.f), 127.f);
    ushort2 o; o.x = f2bf(n0); o.y = f2bf(n1);
    *(ushort2*)(dst + e) = o;
  }
}

// v fp32 (bh,729,72) -> transposed 8-bit integer bf16 vT (bh,80,768)
__global__ __launch_bounds__(256) void v8T_k(const float* __restrict__ vf, ushort_t* __restrict__ vT,
                                             const float* __restrict__ slot) {
  __shared__ float T[64][73];
  int bh = blockIdx.x, k0 = blockIdx.y * 64;
  int tid = threadIdx.x;
  float s8 = fmaxf(*slot, 1e-8f) / 127.f;
  for (int e = tid; e < 64 * 72; e += 256) {
    int r = e / 72, c = e - r * 72;
    T[r][c] = (k0 + r < cS) ? vf[((long)bh * cS + k0 + r) * cD + c] : 0.f;
  }
  __syncthreads();
  for (int e = tid; e < 64 * 80; e += 256) {
    int d = e >> 6, kk = e & 63;
    float val = (d < cD && k0 + kk < cS) ? T[kk][d] : 0.f;
    float n = fminf(fmaxf(rintf(val / s8), -127.f), 127.f);
    vT[((long)bh * cVD + d) * cSP + k0 + kk] = f2bf(n);
  }
}

// ---------------------------------------------------------------------------
// pass A: swapped mfma(K,Q) -> per-row m,Z; global min Z.  1D grid 768,
// XCD-swizzled: all 3 blocks of a bh land on the same XCD (K L2-resident).
// 64 q-rows per wave (4 tiles share each K fragment; 4 independent chains).
__global__ __launch_bounds__(256) void qk_statsA(const ushort_t* __restrict__ qb,
                                                 const ushort_t* __restrict__ kb,
                                                 const float* __restrict__ scal,
                                                 float* __restrict__ rowM, float* __restrict__ rowZ,
                                                 unsigned int* __restrict__ minZ) {
  int wg = blockIdx.x;                 // 768 = 8 xcd * 96
  int xcd = wg & 7, rr = wg >> 3;
  int qt = rr % 3, bh = xcd + 8 * (rr / 3);
  int w = threadIdx.x >> 6, lane = threadIdx.x & 63;
  int lr = lane & 15, lg = lane >> 4;
  int q0 = qt * 256 + w * 64;
  float f = (fmaxf(scal[5], 1e-8f) / 127.f) * (fmaxf(scal[6], 1e-8f) / 127.f) * cScale;
  bf16x8 qa[4][3];
#pragma unroll
  for (int ti = 0; ti < 4; ++ti) {
    const ushort_t* Qp = qb + ((long)bh * cSP + q0 + ti * 16 + lr) * cDP96 + lg * 8;
    qa[ti][0] = *(const bf16x8*)(Qp);
    qa[ti][1] = *(const bf16x8*)(Qp + 32);
    qa[ti][2] = *(const bf16x8*)(Qp + 64);
  }
  const ushort_t* Kp0 = kb + ((long)bh * cSP + lr) * cDP96 + lg * 8;
  float m[4] = {-INFINITY, -INFINITY, -INFINITY, -INFINITY};
  float z[4] = {0.f, 0.f, 0.f, 0.f};
  for (int k0 = 0; k0 < 736; k0 += 16) {
    const ushort_t* Kp = Kp0 + (long)k0 * cDP96;
    bf16x8 kA = *(const bf16x8*)(Kp);
    bf16x8 kB = *(const bf16x8*)(Kp + 32);
    bf16x8 kC = *(const bf16x8*)(Kp + 64);
    int kbase = k0 + lg * 4;
    bool v0 = kbase + 0 < cS, v1 = kbase + 1 < cS, v2 = kbase + 2 < cS, v3 = kbase + 3 < cS;
#pragma unroll
    for (int ti = 0; ti < 4; ++ti) {
      f32x4 acc = {0.f, 0.f, 0.f, 0.f};
      acc = MFMA16(kA, qa[ti][0], acc, 0, 0, 0);
      acc = MFMA16(kB, qa[ti][1], acc, 0, 0, 0);
      acc = MFMA16(kC, qa[ti][2], acc, 0, 0, 0);
      float l0 = v0 ? acc[0] * f : -INFINITY;
      float l1 = v1 ? acc[1] * f : -INFINITY;
      float l2 = v2 ? acc[2] * f : -INFINITY;
      float l3 = v3 ? acc[3] * f : -INFINITY;
      float tm = fmaxf(fmaxf(l0, l1), fmaxf(l2, l3));
      float mn = fmaxf(m[ti], tm);
      z[ti] = z[ti] * __expf(m[ti] - mn) + __expf(l0 - mn) + __expf(l1 - mn) + __expf(l2 - mn) + __expf(l3 - mn);
      m[ti] = mn;
    }
  }
  float zs = __uint_as_float(0x7f800000u);
#pragma unroll
  for (int ti = 0; ti < 4; ++ti) {
#pragma unroll
    for (int o = 16; o <= 32; o <<= 1) {
      float mo = __shfl_xor(m[ti], o);
      float zo = __shfl_xor(z[ti], o);
      float mn = fmaxf(m[ti], mo);
      z[ti] = z[ti] * __expf(m[ti] - mn) + zo * __expf(mo - mn);
      m[ti] = mn;
    }
    int q = q0 + ti * 16 + lr;
    if (lane < 16 && q < cS) {
      rowM[(long)bh * cS + q] = m[ti];
      rowZ[(long)bh * cS + q] = z[ti];
    }
    if (q < cS) zs = fminf(zs, z[ti]);
  }
#pragma unroll
  for (int o = 1; o < 16; o <<= 1) zs = fminf(zs, __shfl_xor(zs, o));
  if (lane == 0) atomicMin(minZ, __float_as_uint(zs));
}

// ---------------------------------------------------------------------------
// pass B fused, wave-independent, 32 q-rows per wave.  1D grid 1536,
// XCD-swizzled: all 6 blocks of a bh land on the same XCD (K,V L2-resident).
// P = fq16(softmax) -> P (nontemporal), attn = P @ v * sv, fused absmax.
__global__ __launch_bounds__(256) void qk_pv(const ushort_t* __restrict__ qb,
                                             const ushort_t* __restrict__ kb,
                                             const ushort_t* __restrict__ vT,
                                             const float* __restrict__ rowM, const float* __restrict__ rowZ,
                                             float* __restrict__ scal,
                                             float* __restrict__ P, float* __restrict__ attn) {
  __shared__ float Pt[4][32][68];   // per-wave slice, 2 tiles of 16 rows
  int wg = blockIdx.x;              // 1536 = 8 xcd * 192
  int xcd = wg & 7, rr = wg >> 3;
  int qt = rr % 6, bh = xcd + 8 * (rr / 6);
  int tid = threadIdx.x, w = tid >> 6, lane = tid & 63;
  int lr = lane & 15, lg = lane >> 4;
  int qw = qt * 128 + w * 32;
  float f = (fmaxf(scal[5], 1e-8f) / 127.f) * (fmaxf(scal[6], 1e-8f) / 127.f) * cScale;
  float sv = fmaxf(scal[7], 1e-8f) / 127.f;
  float sp = fmaxf(1.0f / scal[8], 1e-8f) / 32767.f;
  float mr[2][4], cr[2][4];
#pragma unroll
  for (int ti = 0; ti < 2; ++ti)
#pragma unroll
    for (int r = 0; r < 4; ++r) {
      int qq = qw + ti * 16 + lg * 4 + r;
      bool v = qq < cS;
      mr[ti][r] = v ? rowM[(long)bh * cS + qq] : 0.f;
      float Z = v ? rowZ[(long)bh * cS + qq] : 1.f;
      cr[ti][r] = v ? 1.0f / (Z * sp) : 0.f;
    }
  bf16x8 qa[2][3];
#pragma unroll
  for (int ti = 0; ti < 2; ++ti) {
    const ushort_t* Qp = qb + ((long)bh * cSP + qw + ti * 16 + lr) * cDP96 + lg * 8;
    qa[ti][0] = *(const bf16x8*)(Qp);
    qa[ti][1] = *(const bf16x8*)(Qp + 32);
    qa[ti][2] = *(const bf16x8*)(Qp + 64);
  }

  const ushort_t* Kbase = kb + (long)bh * cSP * cDP96 + (long)lr * cDP96 + lg * 8;
#define LOADK(dst, k0_)                                                        \
  do {                                                                         \
    _Pragma("unroll") for (int t = 0; t < 4; ++t)                              \
      _Pragma("unroll") for (int s = 0; s < 3; ++s)                            \
        dst[t * 3 + s] = *(const bf16x8*)(Kbase + ((long)((k0_) + t * 16)) * cDP96 + s * 32); \
  } while (0)

  bf16x8 kf[12];
  LOADK(kf, 0);
  f32x4 accPV[2][5] = {};
  for (int c = 0; c < 12; ++c) {
    int k0 = c * 64;
    // ---- QK: 4 n-tiles x 2 q-tiles
#pragma unroll
    for (int t = 0; t < 4; ++t) {
      f32x4 a0 = {0.f, 0.f, 0.f, 0.f};
      f32x4 a1 = {0.f, 0.f, 0.f, 0.f};
      a0 = MFMA16(qa[0][0], kf[t * 3 + 0], a0, 0, 0, 0);
      a1 = MFMA16(qa[1][0], kf[t * 3 + 0], a1, 0, 0, 0);
      a0 = MFMA16(qa[0][1], kf[t * 3 + 1], a0, 0, 0, 0);
      a1 = MFMA16(qa[1][1], kf[t * 3 + 1], a1, 0, 0, 0);
      a0 = MFMA16(qa[0][2], kf[t * 3 + 2], a0, 0, 0, 0);
      a1 = MFMA16(qa[1][2], kf[t * 3 + 2], a1, 0, 0, 0);
      bool kval = (k0 + t * 16 + lr) < cS;
#pragma unroll
      for (int r = 0; r < 4; ++r) {
        float e0 = __expf(a0[r] * f - mr[0][r]);
        float n0 = fminf(rintf(e0 * cr[0][r]), 32767.f);
        Pt[w][lg * 4 + r][t * 16 + lr] = kval ? n0 * sp : 0.f;
        float e1 = __expf(a1[r] * f - mr[1][r]);
        float n1 = fminf(rintf(e1 * cr[1][r]), 32767.f);
        Pt[w][16 + lg * 4 + r][t * 16 + lr] = kval ? n1 * sp : 0.f;
      }
    }
    __builtin_amdgcn_wave_barrier();
    // ---- prefetch next chunk's K in place (retires under P store + PV)
    if (c < 11) LOADK(kf, k0 + 64);
    // ---- V frags for both halves, issued before P-store so L2 latency hides
    bf16x8 vfr[2][5];
#pragma unroll
    for (int ks = 0; ks < 2; ++ks)
#pragma unroll
      for (int dt = 0; dt < 5; ++dt)
        vfr[ks][dt] = *(const bf16x8*)(vT + ((long)bh * cVD + dt * 16 + lr) * cSP + k0 + ks * 32 + lg * 8);
    // ---- P write: nontemporal (never re-read on device)
    if (k0 + 64 <= cS) {
#pragma unroll
      for (int it = 0; it < 8; ++it) {
        int e = it * 64 + lane;
        int row = e >> 4, c4 = e & 15;
        int q = qw + row;
        if (q < cS) {
          f32x4 pv4 = *(const f32x4*)&Pt[w][row][c4 * 4];
          __builtin_nontemporal_store(pv4, (f32x4*)&P[((long)bh * cS + q) * cS + k0 + c4 * 4]);
        }
      }
    } else {
      int ncol = cS - k0;
#pragma unroll 4
      for (int j = 0; j < 32; ++j) {
        int q = qw + j;
        if (q < cS && lane < ncol)
          __builtin_nontemporal_store(Pt[w][j][lane], &P[((long)bh * cS + q) * cS + k0 + lane]);
      }
    }
    __builtin_amdgcn_wave_barrier();
    // ---- PV: A = P rows (Dekker hi/lo bf16), B = vT
#pragma unroll
    for (int ks = 0; ks < 2; ++ks) {
#pragma unroll
      for (int ti = 0; ti < 2; ++ti) {
        const float* prow = &Pt[w][ti * 16 + lr][ks * 32 + lg * 8];
        bf16x8 hif, lof;
#pragma unroll
        for (int i = 0; i < 8; ++i) {
          float p = prow[i];
          unsigned short hu = f2bf(p);
          float lo = p - bf2f(hu);
          hif[i] = (short)hu;
          lof[i] = (short)f2bf(lo);
        }
#pragma unroll
        for (int dt = 0; dt < 5; ++dt) {
          accPV[ti][dt] = MFMA16(hif, vfr[ks][dt], accPV[ti][dt], 0, 0, 0);
          accPV[ti][dt] = MFMA16(lof, vfr[ks][dt], accPV[ti][dt], 0, 0, 0);
        }
      }
    }
    __builtin_amdgcn_wave_barrier();
  }
#undef LOADK
  int b = bh >> 4, h = bh & 15;
  float amx = 0.f;
#pragma unroll
  for (int ti = 0; ti < 2; ++ti)
#pragma unroll
    for (int dt = 0; dt < 5; ++dt)
#pragma unroll
      for (int r = 0; r < 4; ++r) {
        int q = qw + ti * 16 + lg * 4 + r, d = dt * 16 + lr;
        if (q < cS && d < cD) {
          float av = accPV[ti][dt][r] * sv;
          attn[((long)(b * cS + q)) * cE + h * cD + d] = av;
          amx = fmaxf(amx, fabsf(av));
        }
      }
  for (int o = 32; o; o >>= 1) amx = fmaxf(amx, __shfl_xor(amx, o));
  if (lane == 0) atomicMax((unsigned int*)(scal + 9), __float_as_uint(amx));
}

// ---------------------------------------------------------------------------
extern "C" void kernel_launch(void* const* d_in, const int* in_sizes, int n_in,
                              void* d_out, int out_size, void* d_ws, size_t ws_size,
                              hipStream_t stream) {
  (void)in_sizes; (void)n_in; (void)out_size;
  if (ws_size < WS_TOTAL) return;

  const float* hs = (const float*)d_in[0];
  const float* wq = (const float*)d_in[1];
  const float* bq = (const float*)d_in[2];
  const float* wk = (const float*)d_in[3];
  const float* bk = (const float*)d_in[4];
  const float* wv = (const float*)d_in[5];
  const float* bv = (const float*)d_in[6];
  const float* wo = (const float*)d_in[7];
  const float* bo = (const float*)d_in[8];

  char* ws = (char*)d_ws;
  float* scal = (float*)(ws + B_SCAL);
  char* W2O  = ws + B_W2O;
  char* W2Q  = ws + B_W2Q;    // W2K, W2V follow contiguously
  char* A2   = ws + B_A2;
  ushort_t* vT = (ushort_t*)(ws + B_VT);
  ushort_t* qb = (ushort_t*)(ws + B_QB);
  ushort_t* kb = (ushort_t*)(ws + B_KB);
  float* rowM = (float*)(ws + B_ROWM);
  float* rowZ = (float*)(ws + B_ROWZ);

  float* outb = (float*)d_out;           // attn_output region (also attn scratch)
  float* Pout = outb + cQKV;             // attn_weights region (also Rq/Rk/Rv scratch)
  float* Rq = Pout;
  float* Rk = Pout + cQKV;
  float* Rv = Pout + 2 * cQKV;

  init_k<<<1, 64, 0, stream>>>(scal);

  // absmax of all raw inputs (one launch)
  absmax5_k<<<dim3(512, 5), 256, 0, stream>>>((const float4*)hs, (const float4*)wq, (const float4*)wk,
                                              (const float4*)wv, (const float4*)wo, (unsigned int*)scal);

  // pack weights (one launch) + hidden to i8 hi/lo planes
  packW4_k<<<dim3(324, 4), 256, 0, stream>>>(wq, wk, wv, wo, scal, W2Q, W2O);
  pack8_k<<<3312, 256, 0, stream>>>(hs, scal + 0, A2, cM);

  // merged Q/K/V projection (fused absmax -> slots 5,6,7)
  mgemm_k<0><<<dim3(9, 92, 3), 256, 0, stream>>>(A2, W2Q, bq, bk, bv, Rq, scal);

  // 8-bit integer-bf16 conversions for attention
  qk82_k<<<dim3(4096, 2), 256, 0, stream>>>(Rq, Rk, qb, kb, scal);
  v8T_k<<<dim3(256, 12), 256, 0, stream>>>(Rv, vT, scal + 7);

  // attention (XCD-swizzled 1D grids)
  qk_statsA<<<768, 256, 0, stream>>>(qb, kb, scal, rowM, rowZ, (unsigned int*)(scal + 8));
  qk_pv<<<1536, 256, 0, stream>>>(qb, kb, vT, rowM, rowZ, scal, Pout, outb);

  // O projection: pack attn (slot 9 from qk_pv), GEMM -> final attn_output
  pack8_k<<<3312, 256, 0, stream>>>(outb, scal + 9, A2, cM);
  mgemm_k<1><<<dim3(9, 92, 1), 256, 0, stream>>>(A2, W2O, bo, bo, bo, outb, scal);
}

// Round 11
// 805.204 us; speedup vs baseline: 1.0135x; 1.0135x over previous
//
#include <hip/hip_runtime.h>
#include <cstdint>
#include <cstddef>

// ---------------------------------------------------------------------------
// SiglipAttention fake-quant.  B=16 S=729 E=1152 H=16 D=72.
// Outputs fp32: attn_output (B,S,E) then attn_weights (B,H,S,S).
// Round 11: qk_pv VGPR diet (chunk-scoped K frags, per-ks V frags) to raise
//           occupancy; qk82+v8T merged; NT stores in O-proj epilogue.
// ---------------------------------------------------------------------------

typedef unsigned short ushort_t;

constexpr int   cB = 16, cS = 729, cE = 1152, cH = 16, cD = 72;
constexpr int   cM = cB * cS;                    // 11664
constexpr long  cQKV  = (long)cM * cE;           // 13,436,928
constexpr long  cWN   = (long)cE * cE;           // 1,327,104
constexpr float cScale = 0.11785113019775792f;   // 72^-0.5
constexpr int   cSP = 768;                       // padded S rows for qb/kb
constexpr int   cDP96 = 96;                      // padded D for MFMA K
constexpr int   cVD = 80;                        // vT d-rows (72 used + 8 pad)
constexpr int   cMF = 11776;                     // padded M (92 tiles of 128)
constexpr int   cRB = 2304;                      // i8 row bytes: [h 1152 | l 1152]

// ---- workspace byte offsets (total ~147 MB <= proven 243.7 MB) -------------
constexpr size_t B_SCAL = 0;                                    // 16 f32
constexpr size_t SZ_W2  = (size_t)cE * cRB;                     // 2,654,208
constexpr size_t B_W2O  = 256;
constexpr size_t B_W2Q  = B_W2O + SZ_W2;                        // W2Q,K,V contiguous
constexpr size_t B_A2   = B_W2Q + 3 * SZ_W2;
constexpr size_t SZ_A2  = (size_t)cMF * cRB;                    // 27,131,904
constexpr size_t B_VT   = B_A2 + SZ_A2;
constexpr size_t SZ_VT  = (size_t)256 * cVD * cSP * 2;          // 31,457,280
constexpr size_t B_QB   = B_VT + SZ_VT;
constexpr size_t SZ_QB  = (size_t)256 * cSP * cDP96 * 2;        // 37,748,736
constexpr size_t B_KB   = B_QB + SZ_QB;
constexpr size_t B_ROWM = B_KB + SZ_QB;
constexpr size_t SZ_ROW = (size_t)256 * cS * 4;                 // 746,496
constexpr size_t B_ROWZ = B_ROWM + SZ_ROW;
constexpr size_t WS_TOTAL = B_ROWZ + SZ_ROW;
static_assert(WS_TOTAL <= 243689728, "stay under proven ws size");

// scalar slots: 0 hid,1 wq,2 wk,3 wv,4 wo,5 q,6 k,7 v,8 minZ,9 attn

typedef __attribute__((ext_vector_type(8))) short bf16x8;
typedef __attribute__((ext_vector_type(4))) float f32x4;
typedef __attribute__((ext_vector_type(4))) int   i32x4;
#define MFMA16 __builtin_amdgcn_mfma_f32_16x16x32_bf16
#define MFMAI8 __builtin_amdgcn_mfma_i32_16x16x64_i8

__device__ __forceinline__ unsigned short f2bf(float f) {
  unsigned u = __float_as_uint(f);
  return (unsigned short)((u + 0x7fffu + ((u >> 16) & 1u)) >> 16);   // RNE
}
__device__ __forceinline__ float bf2f(unsigned short h) {
  return __uint_as_float(((unsigned)h) << 16);
}
__device__ __forceinline__ void gload16(const void* g, void* l) {
  __builtin_amdgcn_global_load_lds((const __attribute__((address_space(1))) unsigned int*)g,
                                   (__attribute__((address_space(3))) unsigned int*)l, 16, 0, 0);
}

// ---------------------------------------------------------------------------
__global__ void init_k(float* sc) {
  int t = threadIdx.x;
  if (t < 16) sc[t] = (t == 8) ? __uint_as_float(0x7f800000u) : 0.0f;
}

// consolidated absmax over 5 tensors: blockIdx.y selects tensor -> scal[y]
__global__ __launch_bounds__(256) void absmax5_k(const float4* __restrict__ x0, const float4* __restrict__ x1,
                                                 const float4* __restrict__ x2, const float4* __restrict__ x3,
                                                 const float4* __restrict__ x4, unsigned int* __restrict__ scal) {
  int t = blockIdx.y;
  const float4* x = (t == 0) ? x0 : (t == 1) ? x1 : (t == 2) ? x2 : (t == 3) ? x3 : x4;
  long n4 = (t == 0) ? cQKV / 4 : cWN / 4;
  float m = 0.f;
  long i = (long)blockIdx.x * blockDim.x + threadIdx.x;
  long str = (long)gridDim.x * blockDim.x;
  for (; i < n4; i += str) {
    float4 v = x[i];
    m = fmaxf(m, fmaxf(fmaxf(fabsf(v.x), fabsf(v.y)), fmaxf(fabsf(v.z), fabsf(v.w))));
  }
  for (int o = 32; o; o >>= 1) m = fmaxf(m, __shfl_xor(m, o));
  __shared__ float red[4];
  int lane = threadIdx.x & 63, w = threadIdx.x >> 6;
  if (!lane) red[w] = m;
  __syncthreads();
  if (threadIdx.x == 0) {
    m = fmaxf(fmaxf(red[0], red[1]), fmaxf(red[2], red[3]));
    atomicMax(&scal[t], __float_as_uint(m));
  }
}

// ---------------------------------------------------------------------------
// fq16 -> integer n -> hi/lo i8 planes: n = 256*a + b (exact except clamp tail)
__global__ __launch_bounds__(256) void pack8_k(const float* __restrict__ src, const float* __restrict__ slot,
                                               char* __restrict__ dst, int nsrc) {
  float s = fmaxf(*slot, 1e-8f) / 32767.f;
  int i = blockIdx.x * 256 + threadIdx.x;
  int r = i / 72, c16 = i - r * 72;
  int m = (r < nsrc) ? r : nsrc - 1;
  const float4* p = (const float4*)(src + (long)m * cE + c16 * 16);
  float4 v[4] = {p[0], p[1], p[2], p[3]};
  const float* xv = (const float*)v;
  unsigned char hb[16] __attribute__((aligned(16)));
  unsigned char lb[16] __attribute__((aligned(16)));
#pragma unroll
  for (int j = 0; j < 16; ++j) {
    float t = rintf(xv[j] / s);
    t = fminf(fmaxf(t, -32767.f), 32767.f);
    float af = floorf(t * 0.00390625f + 0.5f);   // round-half-up to hi byte
    af = fminf(af, 127.f);
    float bf = t - 256.f * af;
    bf = fminf(fmaxf(bf, -128.f), 127.f);
    hb[j] = (unsigned char)((int)af & 0xff);
    lb[j] = (unsigned char)((int)bf & 0xff);
  }
  char* d = dst + (long)r * cRB + c16 * 16;
  *(uint4*)d = *(const uint4*)hb;
  *(uint4*)(d + 1152) = *(const uint4*)lb;
}

// consolidated weight pack: blockIdx.y = z (0 wq,1 wk,2 wv,3 wo)
__global__ __launch_bounds__(256) void packW4_k(const float* __restrict__ w0, const float* __restrict__ w1,
                                                const float* __restrict__ w2, const float* __restrict__ w3,
                                                const float* __restrict__ scal,
                                                char* __restrict__ W2Q, char* __restrict__ W2O) {
  int z = blockIdx.y;
  const float* src = (z == 0) ? w0 : (z == 1) ? w1 : (z == 2) ? w2 : w3;
  char* dst = (z < 3) ? (W2Q + (size_t)z * SZ_W2) : W2O;
  float s = fmaxf(scal[1 + z], 1e-8f) / 32767.f;
  int i = blockIdx.x * 256 + threadIdx.x;
  int r = i / 72, c16 = i - r * 72;
  const float4* p = (const float4*)(src + (long)r * cE + c16 * 16);
  float4 v[4] = {p[0], p[1], p[2], p[3]};
  const float* xv = (const float*)v;
  unsigned char hb[16] __attribute__((aligned(16)));
  unsigned char lb[16] __attribute__((aligned(16)));
#pragma unroll
  for (int j = 0; j < 16; ++j) {
    float t = rintf(xv[j] / s);
    t = fminf(fmaxf(t, -32767.f), 32767.f);
    float af = floorf(t * 0.00390625f + 0.5f);
    af = fminf(af, 127.f);
    float bf = t - 256.f * af;
    bf = fminf(fmaxf(bf, -128.f), 127.f);
    hb[j] = (unsigned char)((int)af & 0xff);
    lb[j] = (unsigned char)((int)bf & 0xff);
  }
  char* d = dst + (long)r * cRB + c16 * 16;
  *(uint4*)d = *(const uint4*)hb;
  *(uint4*)(d + 1152) = *(const uint4*)lb;
}

// ---------------------------------------------------------------------------
// int8 MFMA GEMM (math unchanged, verified).  OM 1 gains NT stores.
template <int OM>
__global__ __launch_bounds__(256, 2) void mgemm_k(const char* __restrict__ A2,
                                                  const char* __restrict__ W2base,
                                                  const float* __restrict__ b0, const float* __restrict__ b1,
                                                  const float* __restrict__ b2,
                                                  float* __restrict__ outbase, float* __restrict__ scal) {
  __shared__ char L[2][32768];
  int z = (OM == 0) ? blockIdx.z : 0;
  const char* W2 = W2base + (size_t)z * cE * cRB;
  const float* bias = (z == 0) ? b0 : (z == 1) ? b1 : b2;
  float* out = outbase + (long)z * cQKV;
  float sA = fmaxf(scal[OM == 0 ? 0 : 9], 1e-8f) / 32767.f;
  float sW = fmaxf(scal[OM == 0 ? 1 + z : 4], 1e-8f) / 32767.f;
  float sc = sA * sW;

  int tid = threadIdx.x, w = tid >> 6, lane = tid & 63;
  int lr = lane & 15, kc = lane >> 4;
  int mt = blockIdx.y * 128, nt = blockIdx.x * 128;
  int wr = (w >> 1) * 64, wc = (w & 1) * 64;

  bool isA = (w < 2);
  const char* mat = isA ? (A2 + (long)mt * cRB) : (W2 + (long)nt * cRB);
  const char* src[8];
  int ldo[8];
#pragma unroll
  for (int j = 0; j < 8; ++j) {
    int seg = (w & 1) * 8 + j;
    int o = seg * 1024 + lane * 16;
    int row = o >> 7, chs = (o >> 4) & 7, orig = chs ^ (row & 7);
    src[j] = mat + (long)row * cRB + (orig >> 2) * 1152 + (orig & 3) * 16;
    ldo[j] = (isA ? 0 : 16384) + seg * 1024;
  }

  int aoffH[4], aoffL[4], boffH[4], boffL[4];
#pragma unroll
  for (int i = 0; i < 4; ++i) {
    int ra = wr + i * 16 + lr;
    aoffH[i] = ra * 128 + ((kc ^ (ra & 7)) << 4);
    aoffL[i] = ra * 128 + (((kc + 4) ^ (ra & 7)) << 4);
    int rb = wc + i * 16 + lr;
    boffH[i] = 16384 + rb * 128 + ((kc ^ (rb & 7)) << 4);
    boffL[i] = 16384 + rb * 128 + (((kc + 4) ^ (rb & 7)) << 4);
  }

  auto stage = [&](int buf, int kk) {
#pragma unroll
    for (int j = 0; j < 8; ++j)
      gload16(src[j] + (long)kk * 64, &L[buf][ldo[j]]);
  };

  i32x4 P1[4][4] = {};
  i32x4 Pm[4][4] = {};
  stage(0, 0);
  __syncthreads();
  int cur = 0;
  for (int kk = 0; kk < 18; ++kk) {
    if (kk < 17) stage(cur ^ 1, kk + 1);
    i32x4 ah[4], al[4], whf[4], wlf[4];
#pragma unroll
    for (int i = 0; i < 4; ++i) {
      ah[i]  = *(const i32x4*)&L[cur][aoffH[i]];
      al[i]  = *(const i32x4*)&L[cur][aoffL[i]];
      whf[i] = *(const i32x4*)&L[cur][boffH[i]];
      wlf[i] = *(const i32x4*)&L[cur][boffL[i]];
    }
#pragma unroll
    for (int i = 0; i < 4; ++i)
#pragma unroll
      for (int j = 0; j < 4; ++j) {
        P1[i][j] = MFMAI8(ah[i], whf[j], P1[i][j], 0, 0, 0);
        Pm[i][j] = MFMAI8(ah[i], wlf[j], Pm[i][j], 0, 0, 0);
        Pm[i][j] = MFMAI8(al[i], whf[j], Pm[i][j], 0, 0, 0);
      }
    __syncthreads();
    cur ^= 1;
  }

  float amx = 0.f;
#pragma unroll
  for (int i = 0; i < 4; ++i) {
#pragma unroll
    for (int r = 0; r < 4; ++r) {
      int m = mt + wr + i * 16 + kc * 4 + r;
      if (m >= cM) continue;
      int b = m / cS, s = m - b * cS;
#pragma unroll
      for (int j = 0; j < 4; ++j) {
        int n = nt + wc + j * 16 + lr;
        float val = 65536.f * (float)P1[i][j][r] + 256.f * (float)Pm[i][j][r];
        float cv = sc * val + bias[n];
        if (OM == 1) {
          __builtin_nontemporal_store(cv, &out[(long)m * cE + n]);
        } else {
          int h = n / cD, d = n - h * cD;
          out[((long)(b * cH + h) * cS + s) * cD + d] = cv;
          amx = fmaxf(amx, fabsf(cv));
        }
      }
    }
  }
  if (OM == 0) {
    for (int o = 32; o; o >>= 1) amx = fmaxf(amx, __shfl_xor(amx, o));
    if (lane == 0) atomicMax((unsigned int*)(scal + 5 + z), __float_as_uint(amx));
  }
}

// ---------------------------------------------------------------------------
// merged conversions: z=0 q -> qb, z=1 k -> kb (integer-bf16, (bh,768,96));
// z=2 v -> vT transposed (bh,80,768).
__global__ __launch_bounds__(256) void qkv8_k(const float* __restrict__ Rq, const float* __restrict__ Rk,
                                              const float* __restrict__ Rv,
                                              ushort_t* __restrict__ qb, ushort_t* __restrict__ kb,
                                              ushort_t* __restrict__ vT, const float* __restrict__ scal) {
  __shared__ float T[64][73];
  int z = blockIdx.y;
  if (z < 2) {
    const float* src = z ? Rk : Rq;
    ushort_t* dst = z ? kb : qb;
    float s8 = fmaxf(scal[5 + z], 1e-8f) / 127.f;
    long total2 = (long)256 * cSP * cDP96 / 2;
    long i = (long)blockIdx.x * blockDim.x + threadIdx.x;
    long str = (long)gridDim.x * blockDim.x;
    for (; i < total2; i += str) {
      long e = i * 2;
      int d = (int)(e % cDP96);
      long rem = e / cDP96;
      int s = (int)(rem % cSP);
      int bh = (int)(rem / cSP);
      float v0 = 0.f, v1 = 0.f;
      if (s < cS && d < cD) {
        const float* p = src + ((long)bh * cS + s) * cD + d;
        v0 = p[0]; v1 = p[1];
      }
      float n0 = fminf(fmaxf(rintf(v0 / s8), -127.f), 127.f);
      float n1 = fminf(fmaxf(rintf(v1 / s8), -127.f), 127.f);
      ushort2 o; o.x = f2bf(n0); o.y = f2bf(n1);
      *(ushort2*)(dst + e) = o;
    }
  } else {
    int bx = blockIdx.x;
    if (bx >= 3072) return;             // 256 bh x 12 k-tiles
    int bh = bx / 12, k0 = (bx - (bx / 12) * 12) * 64;
    int tid = threadIdx.x;
    float s8 = fmaxf(scal[7], 1e-8f) / 127.f;
    for (int e = tid; e < 64 * 72; e += 256) {
      int r = e / 72, c = e - r * 72;
      T[r][c] = (k0 + r < cS) ? Rv[((long)bh * cS + k0 + r) * cD + c] : 0.f;
    }
    __syncthreads();
    for (int e = tid; e < 64 * 80; e += 256) {
      int d = e >> 6, kk = e & 63;
      float val = (d < cD && k0 + kk < cS) ? T[kk][d] : 0.f;
      float n = fminf(fmaxf(rintf(val / s8), -127.f), 127.f);
      vT[((long)bh * cVD + d) * cSP + k0 + kk] = f2bf(n);
    }
  }
}

// ---------------------------------------------------------------------------
// pass A: swapped mfma(K,Q) -> per-row m,Z; global min Z.  1D grid 768,
// XCD-swizzled.  64 q-rows per wave (4 tiles share each K fragment).
__global__ __launch_bounds__(256) void qk_statsA(const ushort_t* __restrict__ qb,
                                                 const ushort_t* __restrict__ kb,
                                                 const float* __restrict__ scal,
                                                 float* __restrict__ rowM, float* __restrict__ rowZ,
                                                 unsigned int* __restrict__ minZ) {
  int wg = blockIdx.x;                 // 768 = 8 xcd * 96
  int xcd = wg & 7, rr = wg >> 3;
  int qt = rr % 3, bh = xcd + 8 * (rr / 3);
  int w = threadIdx.x >> 6, lane = threadIdx.x & 63;
  int lr = lane & 15, lg = lane >> 4;
  int q0 = qt * 256 + w * 64;
  float f = (fmaxf(scal[5], 1e-8f) / 127.f) * (fmaxf(scal[6], 1e-8f) / 127.f) * cScale;
  bf16x8 qa[4][3];
#pragma unroll
  for (int ti = 0; ti < 4; ++ti) {
    const ushort_t* Qp = qb + ((long)bh * cSP + q0 + ti * 16 + lr) * cDP96 + lg * 8;
    qa[ti][0] = *(const bf16x8*)(Qp);
    qa[ti][1] = *(const bf16x8*)(Qp + 32);
    qa[ti][2] = *(const bf16x8*)(Qp + 64);
  }
  const ushort_t* Kp0 = kb + ((long)bh * cSP + lr) * cDP96 + lg * 8;
  float m[4] = {-INFINITY, -INFINITY, -INFINITY, -INFINITY};
  float z[4] = {0.f, 0.f, 0.f, 0.f};
  for (int k0 = 0; k0 < 736; k0 += 16) {
    const ushort_t* Kp = Kp0 + (long)k0 * cDP96;
    bf16x8 kA = *(const bf16x8*)(Kp);
    bf16x8 kB = *(const bf16x8*)(Kp + 32);
    bf16x8 kC = *(const bf16x8*)(Kp + 64);
    int kbase = k0 + lg * 4;
    bool v0 = kbase + 0 < cS, v1 = kbase + 1 < cS, v2 = kbase + 2 < cS, v3 = kbase + 3 < cS;
#pragma unroll
    for (int ti = 0; ti < 4; ++ti) {
      f32x4 acc = {0.f, 0.f, 0.f, 0.f};
      acc = MFMA16(kA, qa[ti][0], acc, 0, 0, 0);
      acc = MFMA16(kB, qa[ti][1], acc, 0, 0, 0);
      acc = MFMA16(kC, qa[ti][2], acc, 0, 0, 0);
      float l0 = v0 ? acc[0] * f : -INFINITY;
      float l1 = v1 ? acc[1] * f : -INFINITY;
      float l2 = v2 ? acc[2] * f : -INFINITY;
      float l3 = v3 ? acc[3] * f : -INFINITY;
      float tm = fmaxf(fmaxf(l0, l1), fmaxf(l2, l3));
      float mn = fmaxf(m[ti], tm);
      z[ti] = z[ti] * __expf(m[ti] - mn) + __expf(l0 - mn) + __expf(l1 - mn) + __expf(l2 - mn) + __expf(l3 - mn);
      m[ti] = mn;
    }
  }
  float zs = __uint_as_float(0x7f800000u);
#pragma unroll
  for (int ti = 0; ti < 4; ++ti) {
#pragma unroll
    for (int o = 16; o <= 32; o <<= 1) {
      float mo = __shfl_xor(m[ti], o);
      float zo = __shfl_xor(z[ti], o);
      float mn = fmaxf(m[ti], mo);
      z[ti] = z[ti] * __expf(m[ti] - mn) + zo * __expf(mo - mn);
      m[ti] = mn;
    }
    int q = q0 + ti * 16 + lr;
    if (lane < 16 && q < cS) {
      rowM[(long)bh * cS + q] = m[ti];
      rowZ[(long)bh * cS + q] = z[ti];
    }
    if (q < cS) zs = fminf(zs, z[ti]);
  }
#pragma unroll
  for (int o = 1; o < 16; o <<= 1) zs = fminf(zs, __shfl_xor(zs, o));
  if (lane == 0) atomicMin(minZ, __float_as_uint(zs));
}

// ---------------------------------------------------------------------------
// pass B fused, wave-independent, 32 q-rows per wave.  1D grid 1536,
// XCD-swizzled.  K frags chunk-scoped, V frags per-ks (VGPR diet).
__global__ __launch_bounds__(256) void qk_pv(const ushort_t* __restrict__ qb,
                                             const ushort_t* __restrict__ kb,
                                             const ushort_t* __restrict__ vT,
                                             const float* __restrict__ rowM, const float* __restrict__ rowZ,
                                             float* __restrict__ scal,
                                             float* __restrict__ P, float* __restrict__ attn) {
  __shared__ float Pt[4][32][68];   // per-wave slice, 2 tiles of 16 rows
  int wg = blockIdx.x;              // 1536 = 8 xcd * 192
  int xcd = wg & 7, rr = wg >> 3;
  int qt = rr % 6, bh = xcd + 8 * (rr / 6);
  int tid = threadIdx.x, w = tid >> 6, lane = tid & 63;
  int lr = lane & 15, lg = lane >> 4;
  int qw = qt * 128 + w * 32;
  float f = (fmaxf(scal[5], 1e-8f) / 127.f) * (fmaxf(scal[6], 1e-8f) / 127.f) * cScale;
  float sv = fmaxf(scal[7], 1e-8f) / 127.f;
  float sp = fmaxf(1.0f / scal[8], 1e-8f) / 32767.f;
  float mr[2][4], cr[2][4];
#pragma unroll
  for (int ti = 0; ti < 2; ++ti)
#pragma unroll
    for (int r = 0; r < 4; ++r) {
      int qq = qw + ti * 16 + lg * 4 + r;
      bool v = qq < cS;
      mr[ti][r] = v ? rowM[(long)bh * cS + qq] : 0.f;
      float Z = v ? rowZ[(long)bh * cS + qq] : 1.f;
      cr[ti][r] = v ? 1.0f / (Z * sp) : 0.f;
    }
  bf16x8 qa[2][3];
#pragma unroll
  for (int ti = 0; ti < 2; ++ti) {
    const ushort_t* Qp = qb + ((long)bh * cSP + qw + ti * 16 + lr) * cDP96 + lg * 8;
    qa[ti][0] = *(const bf16x8*)(Qp);
    qa[ti][1] = *(const bf16x8*)(Qp + 32);
    qa[ti][2] = *(const bf16x8*)(Qp + 64);
  }

  const ushort_t* Kbase = kb + (long)bh * cSP * cDP96 + (long)lr * cDP96 + lg * 8;
  f32x4 accPV[2][5] = {};
  for (int c = 0; c < 12; ++c) {
    int k0 = c * 64;
    // ---- QK: K frags scoped to this phase (dead before PV -> lower VGPR)
    {
      bf16x8 kf[12];
#pragma unroll
      for (int t = 0; t < 4; ++t)
#pragma unroll
        for (int s = 0; s < 3; ++s)
          kf[t * 3 + s] = *(const bf16x8*)(Kbase + (long)(k0 + t * 16) * cDP96 + s * 32);
#pragma unroll
      for (int t = 0; t < 4; ++t) {
        f32x4 a0 = {0.f, 0.f, 0.f, 0.f};
        f32x4 a1 = {0.f, 0.f, 0.f, 0.f};
        a0 = MFMA16(qa[0][0], kf[t * 3 + 0], a0, 0, 0, 0);
        a1 = MFMA16(qa[1][0], kf[t * 3 + 0], a1, 0, 0, 0);
        a0 = MFMA16(qa[0][1], kf[t * 3 + 1], a0, 0, 0, 0);
        a1 = MFMA16(qa[1][1], kf[t * 3 + 1], a1, 0, 0, 0);
        a0 = MFMA16(qa[0][2], kf[t * 3 + 2], a0, 0, 0, 0);
        a1 = MFMA16(qa[1][2], kf[t * 3 + 2], a1, 0, 0, 0);
        bool kval = (k0 + t * 16 + lr) < cS;
#pragma unroll
        for (int r = 0; r < 4; ++r) {
          float e0 = __expf(a0[r] * f - mr[0][r]);
          float n0 = fminf(rintf(e0 * cr[0][r]), 32767.f);
          Pt[w][lg * 4 + r][t * 16 + lr] = kval ? n0 * sp : 0.f;
          float e1 = __expf(a1[r] * f - mr[1][r]);
          float n1 = fminf(rintf(e1 * cr[1][r]), 32767.f);
          Pt[w][16 + lg * 4 + r][t * 16 + lr] = kval ? n1 * sp : 0.f;
        }
      }
    }
    __builtin_amdgcn_wave_barrier();
    // ---- P write: nontemporal (never re-read on device)
    if (k0 + 64 <= cS) {
#pragma unroll
      for (int it = 0; it < 8; ++it) {
        int e = it * 64 + lane;
        int row = e >> 4, c4 = e & 15;
        int q = qw + row;
        if (q < cS) {
          f32x4 pv4 = *(const f32x4*)&Pt[w][row][c4 * 4];
          __builtin_nontemporal_store(pv4, (f32x4*)&P[((long)bh * cS + q) * cS + k0 + c4 * 4]);
        }
      }
    } else {
      int ncol = cS - k0;
#pragma unroll 4
      for (int j = 0; j < 32; ++j) {
        int q = qw + j;
        if (q < cS && lane < ncol)
          __builtin_nontemporal_store(Pt[w][j][lane], &P[((long)bh * cS + q) * cS + k0 + lane]);
      }
    }
    __builtin_amdgcn_wave_barrier();
    // ---- PV: A = P rows (Dekker hi/lo bf16), B = vT (per-ks V frags)
#pragma unroll
    for (int ks = 0; ks < 2; ++ks) {
      bf16x8 vf5[5];
#pragma unroll
      for (int dt = 0; dt < 5; ++dt)
        vf5[dt] = *(const bf16x8*)(vT + ((long)bh * cVD + dt * 16 + lr) * cSP + k0 + ks * 32 + lg * 8);
#pragma unroll
      for (int ti = 0; ti < 2; ++ti) {
        const float* prow = &Pt[w][ti * 16 + lr][ks * 32 + lg * 8];
        bf16x8 hif, lof;
#pragma unroll
        for (int i = 0; i < 8; ++i) {
          float p = prow[i];
          unsigned short hu = f2bf(p);
          float lo = p - bf2f(hu);
          hif[i] = (short)hu;
          lof[i] = (short)f2bf(lo);
        }
#pragma unroll
        for (int dt = 0; dt < 5; ++dt) {
          accPV[ti][dt] = MFMA16(hif, vf5[dt], accPV[ti][dt], 0, 0, 0);
          accPV[ti][dt] = MFMA16(lof, vf5[dt], accPV[ti][dt], 0, 0, 0);
        }
      }
    }
    __builtin_amdgcn_wave_barrier();
  }
  int b = bh >> 4, h = bh & 15;
  float amx = 0.f;
#pragma unroll
  for (int ti = 0; ti < 2; ++ti)
#pragma unroll
    for (int dt = 0; dt < 5; ++dt)
#pragma unroll
      for (int r = 0; r < 4; ++r) {
        int q = qw + ti * 16 + lg * 4 + r, d = dt * 16 + lr;
        if (q < cS && d < cD) {
          float av = accPV[ti][dt][r] * sv;
          attn[((long)(b * cS + q)) * cE + h * cD + d] = av;
          amx = fmaxf(amx, fabsf(av));
        }
      }
  for (int o = 32; o; o >>= 1) amx = fmaxf(amx, __shfl_xor(amx, o));
  if (lane == 0) atomicMax((unsigned int*)(scal + 9), __float_as_uint(amx));
}

// ---------------------------------------------------------------------------
extern "C" void kernel_launch(void* const* d_in, const int* in_sizes, int n_in,
                              void* d_out, int out_size, void* d_ws, size_t ws_size,
                              hipStream_t stream) {
  (void)in_sizes; (void)n_in; (void)out_size;
  if (ws_size < WS_TOTAL) return;

  const float* hs = (const float*)d_in[0];
  const float* wq = (const float*)d_in[1];
  const float* bq = (const float*)d_in[2];
  const float* wk = (const float*)d_in[3];
  const float* bk = (const float*)d_in[4];
  const float* wv = (const float*)d_in[5];
  const float* bv = (const float*)d_in[6];
  const float* wo = (const float*)d_in[7];
  const float* bo = (const float*)d_in[8];

  char* ws = (char*)d_ws;
  float* scal = (float*)(ws + B_SCAL);
  char* W2O  = ws + B_W2O;
  char* W2Q  = ws + B_W2Q;    // W2K, W2V follow contiguously
  char* A2   = ws + B_A2;
  ushort_t* vT = (ushort_t*)(ws + B_VT);
  ushort_t* qb = (ushort_t*)(ws + B_QB);
  ushort_t* kb = (ushort_t*)(ws + B_KB);
  float* rowM = (float*)(ws + B_ROWM);
  float* rowZ = (float*)(ws + B_ROWZ);

  float* outb = (float*)d_out;           // attn_output region (also attn scratch)
  float* Pout = outb + cQKV;             // attn_weights region (also Rq/Rk/Rv scratch)
  float* Rq = Pout;
  float* Rk = Pout + cQKV;
  float* Rv = Pout + 2 * cQKV;

  init_k<<<1, 64, 0, stream>>>(scal);

  // absmax of all raw inputs (one launch)
  absmax5_k<<<dim3(512, 5), 256, 0, stream>>>((const float4*)hs, (const float4*)wq, (const float4*)wk,
                                              (const float4*)wv, (const float4*)wo, (unsigned int*)scal);

  // pack weights (one launch) + hidden to i8 hi/lo planes
  packW4_k<<<dim3(324, 4), 256, 0, stream>>>(wq, wk, wv, wo, scal, W2Q, W2O);
  pack8_k<<<3312, 256, 0, stream>>>(hs, scal + 0, A2, cM);

  // merged Q/K/V projection (fused absmax -> slots 5,6,7)
  mgemm_k<0><<<dim3(9, 92, 3), 256, 0, stream>>>(A2, W2Q, bq, bk, bv, Rq, scal);

  // merged q/k/v conversions for attention (one launch)
  qkv8_k<<<dim3(4096, 3), 256, 0, stream>>>(Rq, Rk, Rv, qb, kb, vT, scal);

  // attention (XCD-swizzled 1D grids)
  qk_statsA<<<768, 256, 0, stream>>>(qb, kb, scal, rowM, rowZ, (unsigned int*)(scal + 8));
  qk_pv<<<1536, 256, 0, stream>>>(qb, kb, vT, rowM, rowZ, scal, Pout, outb);

  // O projection: pack attn (slot 9 from qk_pv), GEMM -> final attn_output
  pack8_k<<<3312, 256, 0, stream>>>(outb, scal + 9, A2, cM);
  mgemm_k<1><<<dim3(9, 92, 1), 256, 0, stream>>>(A2, W2O, bo, bo, bo, outb, scal);
}

// Round 12
// 755.338 us; speedup vs baseline: 1.0804x; 1.0660x over previous
//
#include <hip/hip_runtime.h>
#include <cstdint>
#include <cstddef>

// ---------------------------------------------------------------------------
// SiglipAttention fake-quant.  B=16 S=729 E=1152 H=16 D=72.
// Outputs fp32: attn_output (B,S,E) then attn_weights (B,H,S,S).
// Round 12: mgemm XCD-chunked swizzle (z outer, y-panels per XCD) for L2
//           locality; s_setprio around MFMA clusters in attention kernels.
// ---------------------------------------------------------------------------

typedef unsigned short ushort_t;

constexpr int   cB = 16, cS = 729, cE = 1152, cH = 16, cD = 72;
constexpr int   cM = cB * cS;                    // 11664
constexpr long  cQKV  = (long)cM * cE;           // 13,436,928
constexpr long  cWN   = (long)cE * cE;           // 1,327,104
constexpr float cScale = 0.11785113019775792f;   // 72^-0.5
constexpr int   cSP = 768;                       // padded S rows for qb/kb
constexpr int   cDP96 = 96;                      // padded D for MFMA K
constexpr int   cVD = 80;                        // vT d-rows (72 used + 8 pad)
constexpr int   cMF = 11776;                     // padded M (92 tiles of 128)
constexpr int   cRB = 2304;                      // i8 row bytes: [h 1152 | l 1152]

// ---- workspace byte offsets (total ~147 MB <= proven 243.7 MB) -------------
constexpr size_t B_SCAL = 0;                                    // 16 f32
constexpr size_t SZ_W2  = (size_t)cE * cRB;                     // 2,654,208
constexpr size_t B_W2O  = 256;
constexpr size_t B_W2Q  = B_W2O + SZ_W2;                        // W2Q,K,V contiguous
constexpr size_t B_A2   = B_W2Q + 3 * SZ_W2;
constexpr size_t SZ_A2  = (size_t)cMF * cRB;                    // 27,131,904
constexpr size_t B_VT   = B_A2 + SZ_A2;
constexpr size_t SZ_VT  = (size_t)256 * cVD * cSP * 2;          // 31,457,280
constexpr size_t B_QB   = B_VT + SZ_VT;
constexpr size_t SZ_QB  = (size_t)256 * cSP * cDP96 * 2;        // 37,748,736
constexpr size_t B_KB   = B_QB + SZ_QB;
constexpr size_t B_ROWM = B_KB + SZ_QB;
constexpr size_t SZ_ROW = (size_t)256 * cS * 4;                 // 746,496
constexpr size_t B_ROWZ = B_ROWM + SZ_ROW;
constexpr size_t WS_TOTAL = B_ROWZ + SZ_ROW;
static_assert(WS_TOTAL <= 243689728, "stay under proven ws size");

// scalar slots: 0 hid,1 wq,2 wk,3 wv,4 wo,5 q,6 k,7 v,8 minZ,9 attn

typedef __attribute__((ext_vector_type(8))) short bf16x8;
typedef __attribute__((ext_vector_type(4))) float f32x4;
typedef __attribute__((ext_vector_type(4))) int   i32x4;
#define MFMA16 __builtin_amdgcn_mfma_f32_16x16x32_bf16
#define MFMAI8 __builtin_amdgcn_mfma_i32_16x16x64_i8

__device__ __forceinline__ unsigned short f2bf(float f) {
  unsigned u = __float_as_uint(f);
  return (unsigned short)((u + 0x7fffu + ((u >> 16) & 1u)) >> 16);   // RNE
}
__device__ __forceinline__ float bf2f(unsigned short h) {
  return __uint_as_float(((unsigned)h) << 16);
}
__device__ __forceinline__ void gload16(const void* g, void* l) {
  __builtin_amdgcn_global_load_lds((const __attribute__((address_space(1))) unsigned int*)g,
                                   (__attribute__((address_space(3))) unsigned int*)l, 16, 0, 0);
}

// ---------------------------------------------------------------------------
__global__ void init_k(float* sc) {
  int t = threadIdx.x;
  if (t < 16) sc[t] = (t == 8) ? __uint_as_float(0x7f800000u) : 0.0f;
}

// consolidated absmax over 5 tensors: blockIdx.y selects tensor -> scal[y]
__global__ __launch_bounds__(256) void absmax5_k(const float4* __restrict__ x0, const float4* __restrict__ x1,
                                                 const float4* __restrict__ x2, const float4* __restrict__ x3,
                                                 const float4* __restrict__ x4, unsigned int* __restrict__ scal) {
  int t = blockIdx.y;
  const float4* x = (t == 0) ? x0 : (t == 1) ? x1 : (t == 2) ? x2 : (t == 3) ? x3 : x4;
  long n4 = (t == 0) ? cQKV / 4 : cWN / 4;
  float m = 0.f;
  long i = (long)blockIdx.x * blockDim.x + threadIdx.x;
  long str = (long)gridDim.x * blockDim.x;
  for (; i < n4; i += str) {
    float4 v = x[i];
    m = fmaxf(m, fmaxf(fmaxf(fabsf(v.x), fabsf(v.y)), fmaxf(fabsf(v.z), fabsf(v.w))));
  }
  for (int o = 32; o; o >>= 1) m = fmaxf(m, __shfl_xor(m, o));
  __shared__ float red[4];
  int lane = threadIdx.x & 63, w = threadIdx.x >> 6;
  if (!lane) red[w] = m;
  __syncthreads();
  if (threadIdx.x == 0) {
    m = fmaxf(fmaxf(red[0], red[1]), fmaxf(red[2], red[3]));
    atomicMax(&scal[t], __float_as_uint(m));
  }
}

// ---------------------------------------------------------------------------
// fq16 -> integer n -> hi/lo i8 planes: n = 256*a + b (exact except clamp tail)
__global__ __launch_bounds__(256) void pack8_k(const float* __restrict__ src, const float* __restrict__ slot,
                                               char* __restrict__ dst, int nsrc) {
  float s = fmaxf(*slot, 1e-8f) / 32767.f;
  int i = blockIdx.x * 256 + threadIdx.x;
  int r = i / 72, c16 = i - r * 72;
  int m = (r < nsrc) ? r : nsrc - 1;
  const float4* p = (const float4*)(src + (long)m * cE + c16 * 16);
  float4 v[4] = {p[0], p[1], p[2], p[3]};
  const float* xv = (const float*)v;
  unsigned char hb[16] __attribute__((aligned(16)));
  unsigned char lb[16] __attribute__((aligned(16)));
#pragma unroll
  for (int j = 0; j < 16; ++j) {
    float t = rintf(xv[j] / s);
    t = fminf(fmaxf(t, -32767.f), 32767.f);
    float af = floorf(t * 0.00390625f + 0.5f);   // round-half-up to hi byte
    af = fminf(af, 127.f);
    float bf = t - 256.f * af;
    bf = fminf(fmaxf(bf, -128.f), 127.f);
    hb[j] = (unsigned char)((int)af & 0xff);
    lb[j] = (unsigned char)((int)bf & 0xff);
  }
  char* d = dst + (long)r * cRB + c16 * 16;
  *(uint4*)d = *(const uint4*)hb;
  *(uint4*)(d + 1152) = *(const uint4*)lb;
}

// consolidated weight pack: blockIdx.y = z (0 wq,1 wk,2 wv,3 wo)
__global__ __launch_bounds__(256) void packW4_k(const float* __restrict__ w0, const float* __restrict__ w1,
                                                const float* __restrict__ w2, const float* __restrict__ w3,
                                                const float* __restrict__ scal,
                                                char* __restrict__ W2Q, char* __restrict__ W2O) {
  int z = blockIdx.y;
  const float* src = (z == 0) ? w0 : (z == 1) ? w1 : (z == 2) ? w2 : w3;
  char* dst = (z < 3) ? (W2Q + (size_t)z * SZ_W2) : W2O;
  float s = fmaxf(scal[1 + z], 1e-8f) / 32767.f;
  int i = blockIdx.x * 256 + threadIdx.x;
  int r = i / 72, c16 = i - r * 72;
  const float4* p = (const float4*)(src + (long)r * cE + c16 * 16);
  float4 v[4] = {p[0], p[1], p[2], p[3]};
  const float* xv = (const float*)v;
  unsigned char hb[16] __attribute__((aligned(16)));
  unsigned char lb[16] __attribute__((aligned(16)));
#pragma unroll
  for (int j = 0; j < 16; ++j) {
    float t = rintf(xv[j] / s);
    t = fminf(fmaxf(t, -32767.f), 32767.f);
    float af = floorf(t * 0.00390625f + 0.5f);
    af = fminf(af, 127.f);
    float bf = t - 256.f * af;
    bf = fminf(fmaxf(bf, -128.f), 127.f);
    hb[j] = (unsigned char)((int)af & 0xff);
    lb[j] = (unsigned char)((int)bf & 0xff);
  }
  char* d = dst + (long)r * cRB + c16 * 16;
  *(uint4*)d = *(const uint4*)hb;
  *(uint4*)(d + 1152) = *(const uint4*)lb;
}

// ---------------------------------------------------------------------------
// int8 MFMA GEMM (math unchanged, verified).  1D grid with bijective XCD-chunk
// swizzle: consecutive logical tiles (x fastest, then y-panels, z outer) land
// on the same XCD -> A-panels and the active W-plane stay L2-resident.
// OM 0: nwg 2484 (z in {0,1,2}); OM 1: nwg 828, NT stores.
template <int OM>
__global__ __launch_bounds__(256, 2) void mgemm_k(const char* __restrict__ A2,
                                                  const char* __restrict__ W2base,
                                                  const float* __restrict__ b0, const float* __restrict__ b1,
                                                  const float* __restrict__ b2,
                                                  float* __restrict__ outbase, float* __restrict__ scal) {
  __shared__ char L[2][32768];
  // hw block id -> XCD chunk -> logical (z,y,x)
  int bsw = blockIdx.x;
  int c8 = bsw & 7, j8 = bsw >> 3;
  int Lid;
  if (OM == 0) Lid = (c8 < 4 ? c8 * 311 : 1244 + (c8 - 4) * 310) + j8;   // nwg 2484
  else         Lid = (c8 < 4 ? c8 * 104 : 416  + (c8 - 4) * 103) + j8;   // nwg 828
  int z   = (OM == 0) ? Lid / 828 : 0;
  int rem = (OM == 0) ? Lid - z * 828 : Lid;
  int yt = rem / 9, xt = rem - yt * 9;

  const char* W2 = W2base + (size_t)z * cE * cRB;
  const float* bias = (z == 0) ? b0 : (z == 1) ? b1 : b2;
  float* out = outbase + (long)z * cQKV;
  float sA = fmaxf(scal[OM == 0 ? 0 : 9], 1e-8f) / 32767.f;
  float sW = fmaxf(scal[OM == 0 ? 1 + z : 4], 1e-8f) / 32767.f;
  float sc = sA * sW;

  int tid = threadIdx.x, w = tid >> 6, lane = tid & 63;
  int lr = lane & 15, kc = lane >> 4;
  int mt = yt * 128, nt = xt * 128;
  int wr = (w >> 1) * 64, wc = (w & 1) * 64;

  bool isA = (w < 2);
  const char* mat = isA ? (A2 + (long)mt * cRB) : (W2 + (long)nt * cRB);
  const char* src[8];
  int ldo[8];
#pragma unroll
  for (int j = 0; j < 8; ++j) {
    int seg = (w & 1) * 8 + j;
    int o = seg * 1024 + lane * 16;
    int row = o >> 7, chs = (o >> 4) & 7, orig = chs ^ (row & 7);
    src[j] = mat + (long)row * cRB + (orig >> 2) * 1152 + (orig & 3) * 16;
    ldo[j] = (isA ? 0 : 16384) + seg * 1024;
  }

  int aoffH[4], aoffL[4], boffH[4], boffL[4];
#pragma unroll
  for (int i = 0; i < 4; ++i) {
    int ra = wr + i * 16 + lr;
    aoffH[i] = ra * 128 + ((kc ^ (ra & 7)) << 4);
    aoffL[i] = ra * 128 + (((kc + 4) ^ (ra & 7)) << 4);
    int rb = wc + i * 16 + lr;
    boffH[i] = 16384 + rb * 128 + ((kc ^ (rb & 7)) << 4);
    boffL[i] = 16384 + rb * 128 + (((kc + 4) ^ (rb & 7)) << 4);
  }

  auto stage = [&](int buf, int kk) {
#pragma unroll
    for (int j = 0; j < 8; ++j)
      gload16(src[j] + (long)kk * 64, &L[buf][ldo[j]]);
  };

  i32x4 P1[4][4] = {};
  i32x4 Pm[4][4] = {};
  stage(0, 0);
  __syncthreads();
  int cur = 0;
  for (int kk = 0; kk < 18; ++kk) {
    if (kk < 17) stage(cur ^ 1, kk + 1);
    i32x4 ah[4], al[4], whf[4], wlf[4];
#pragma unroll
    for (int i = 0; i < 4; ++i) {
      ah[i]  = *(const i32x4*)&L[cur][aoffH[i]];
      al[i]  = *(const i32x4*)&L[cur][aoffL[i]];
      whf[i] = *(const i32x4*)&L[cur][boffH[i]];
      wlf[i] = *(const i32x4*)&L[cur][boffL[i]];
    }
#pragma unroll
    for (int i = 0; i < 4; ++i)
#pragma unroll
      for (int j = 0; j < 4; ++j) {
        P1[i][j] = MFMAI8(ah[i], whf[j], P1[i][j], 0, 0, 0);
        Pm[i][j] = MFMAI8(ah[i], wlf[j], Pm[i][j], 0, 0, 0);
        Pm[i][j] = MFMAI8(al[i], whf[j], Pm[i][j], 0, 0, 0);
      }
    __syncthreads();
    cur ^= 1;
  }

  float amx = 0.f;
#pragma unroll
  for (int i = 0; i < 4; ++i) {
#pragma unroll
    for (int r = 0; r < 4; ++r) {
      int m = mt + wr + i * 16 + kc * 4 + r;
      if (m >= cM) continue;
      int b = m / cS, s = m - b * cS;
#pragma unroll
      for (int j = 0; j < 4; ++j) {
        int n = nt + wc + j * 16 + lr;
        float val = 65536.f * (float)P1[i][j][r] + 256.f * (float)Pm[i][j][r];
        float cv = sc * val + bias[n];
        if (OM == 1) {
          __builtin_nontemporal_store(cv, &out[(long)m * cE + n]);
        } else {
          int h = n / cD, d = n - h * cD;
          out[((long)(b * cH + h) * cS + s) * cD + d] = cv;
          amx = fmaxf(amx, fabsf(cv));
        }
      }
    }
  }
  if (OM == 0) {
    for (int o = 32; o; o >>= 1) amx = fmaxf(amx, __shfl_xor(amx, o));
    if (lane == 0) atomicMax((unsigned int*)(scal + 5 + z), __float_as_uint(amx));
  }
}

// ---------------------------------------------------------------------------
// merged conversions: z=0 q -> qb, z=1 k -> kb (integer-bf16, (bh,768,96));
// z=2 v -> vT transposed (bh,80,768).
__global__ __launch_bounds__(256) void qkv8_k(const float* __restrict__ Rq, const float* __restrict__ Rk,
                                              const float* __restrict__ Rv,
                                              ushort_t* __restrict__ qb, ushort_t* __restrict__ kb,
                                              ushort_t* __restrict__ vT, const float* __restrict__ scal) {
  __shared__ float T[64][73];
  int z = blockIdx.y;
  if (z < 2) {
    const float* src = z ? Rk : Rq;
    ushort_t* dst = z ? kb : qb;
    float s8 = fmaxf(scal[5 + z], 1e-8f) / 127.f;
    long total2 = (long)256 * cSP * cDP96 / 2;
    long i = (long)blockIdx.x * blockDim.x + threadIdx.x;
    long str = (long)gridDim.x * blockDim.x;
    for (; i < total2; i += str) {
      long e = i * 2;
      int d = (int)(e % cDP96);
      long rem = e / cDP96;
      int s = (int)(rem % cSP);
      int bh = (int)(rem / cSP);
      float v0 = 0.f, v1 = 0.f;
      if (s < cS && d < cD) {
        const float* p = src + ((long)bh * cS + s) * cD + d;
        v0 = p[0]; v1 = p[1];
      }
      float n0 = fminf(fmaxf(rintf(v0 / s8), -127.f), 127.f);
      float n1 = fminf(fmaxf(rintf(v1 / s8), -127.f), 127.f);
      ushort2 o; o.x = f2bf(n0); o.y = f2bf(n1);
      *(ushort2*)(dst + e) = o;
    }
  } else {
    int bx = blockIdx.x;
    if (bx >= 3072) return;             // 256 bh x 12 k-tiles
    int bh = bx / 12, k0 = (bx - (bx / 12) * 12) * 64;
    int tid = threadIdx.x;
    float s8 = fmaxf(scal[7], 1e-8f) / 127.f;
    for (int e = tid; e < 64 * 72; e += 256) {
      int r = e / 72, c = e - r * 72;
      T[r][c] = (k0 + r < cS) ? Rv[((long)bh * cS + k0 + r) * cD + c] : 0.f;
    }
    __syncthreads();
    for (int e = tid; e < 64 * 80; e += 256) {
      int d = e >> 6, kk = e & 63;
      float val = (d < cD && k0 + kk < cS) ? T[kk][d] : 0.f;
      float n = fminf(fmaxf(rintf(val / s8), -127.f), 127.f);
      vT[((long)bh * cVD + d) * cSP + k0 + kk] = f2bf(n);
    }
  }
}

// ---------------------------------------------------------------------------
// pass A: swapped mfma(K,Q) -> per-row m,Z; global min Z.  1D grid 768,
// XCD-swizzled.  64 q-rows per wave; setprio around MFMA cluster.
__global__ __launch_bounds__(256) void qk_statsA(const ushort_t* __restrict__ qb,
                                                 const ushort_t* __restrict__ kb,
                                                 const float* __restrict__ scal,
                                                 float* __restrict__ rowM, float* __restrict__ rowZ,
                                                 unsigned int* __restrict__ minZ) {
  int wg = blockIdx.x;                 // 768 = 8 xcd * 96
  int xcd = wg & 7, rr = wg >> 3;
  int qt = rr % 3, bh = xcd + 8 * (rr / 3);
  int w = threadIdx.x >> 6, lane = threadIdx.x & 63;
  int lr = lane & 15, lg = lane >> 4;
  int q0 = qt * 256 + w * 64;
  float f = (fmaxf(scal[5], 1e-8f) / 127.f) * (fmaxf(scal[6], 1e-8f) / 127.f) * cScale;
  bf16x8 qa[4][3];
#pragma unroll
  for (int ti = 0; ti < 4; ++ti) {
    const ushort_t* Qp = qb + ((long)bh * cSP + q0 + ti * 16 + lr) * cDP96 + lg * 8;
    qa[ti][0] = *(const bf16x8*)(Qp);
    qa[ti][1] = *(const bf16x8*)(Qp + 32);
    qa[ti][2] = *(const bf16x8*)(Qp + 64);
  }
  const ushort_t* Kp0 = kb + ((long)bh * cSP + lr) * cDP96 + lg * 8;
  float m[4] = {-INFINITY, -INFINITY, -INFINITY, -INFINITY};
  float z[4] = {0.f, 0.f, 0.f, 0.f};
  for (int k0 = 0; k0 < 736; k0 += 16) {
    const ushort_t* Kp = Kp0 + (long)k0 * cDP96;
    bf16x8 kA = *(const bf16x8*)(Kp);
    bf16x8 kB = *(const bf16x8*)(Kp + 32);
    bf16x8 kC = *(const bf16x8*)(Kp + 64);
    int kbase = k0 + lg * 4;
    bool v0 = kbase + 0 < cS, v1 = kbase + 1 < cS, v2 = kbase + 2 < cS, v3 = kbase + 3 < cS;
#pragma unroll
    for (int ti = 0; ti < 4; ++ti) {
      f32x4 acc = {0.f, 0.f, 0.f, 0.f};
      __builtin_amdgcn_s_setprio(1);
      acc = MFMA16(kA, qa[ti][0], acc, 0, 0, 0);
      acc = MFMA16(kB, qa[ti][1], acc, 0, 0, 0);
      acc = MFMA16(kC, qa[ti][2], acc, 0, 0, 0);
      __builtin_amdgcn_s_setprio(0);
      float l0 = v0 ? acc[0] * f : -INFINITY;
      float l1 = v1 ? acc[1] * f : -INFINITY;
      float l2 = v2 ? acc[2] * f : -INFINITY;
      float l3 = v3 ? acc[3] * f : -INFINITY;
      float tm = fmaxf(fmaxf(l0, l1), fmaxf(l2, l3));
      float mn = fmaxf(m[ti], tm);
      z[ti] = z[ti] * __expf(m[ti] - mn) + __expf(l0 - mn) + __expf(l1 - mn) + __expf(l2 - mn) + __expf(l3 - mn);
      m[ti] = mn;
    }
  }
  float zs = __uint_as_float(0x7f800000u);
#pragma unroll
  for (int ti = 0; ti < 4; ++ti) {
#pragma unroll
    for (int o = 16; o <= 32; o <<= 1) {
      float mo = __shfl_xor(m[ti], o);
      float zo = __shfl_xor(z[ti], o);
      float mn = fmaxf(m[ti], mo);
      z[ti] = z[ti] * __expf(m[ti] - mn) + zo * __expf(mo - mn);
      m[ti] = mn;
    }
    int q = q0 + ti * 16 + lr;
    if (lane < 16 && q < cS) {
      rowM[(long)bh * cS + q] = m[ti];
      rowZ[(long)bh * cS + q] = z[ti];
    }
    if (q < cS) zs = fminf(zs, z[ti]);
  }
#pragma unroll
  for (int o = 1; o < 16; o <<= 1) zs = fminf(zs, __shfl_xor(zs, o));
  if (lane == 0) atomicMin(minZ, __float_as_uint(zs));
}

// ---------------------------------------------------------------------------
// pass B fused, wave-independent, 32 q-rows per wave.  1D grid 1536,
// XCD-swizzled.  K frags chunk-scoped, V frags per-ks; setprio around MFMA.
__global__ __launch_bounds__(256) void qk_pv(const ushort_t* __restrict__ qb,
                                             const ushort_t* __restrict__ kb,
                                             const ushort_t* __restrict__ vT,
                                             const float* __restrict__ rowM, const float* __restrict__ rowZ,
                                             float* __restrict__ scal,
                                             float* __restrict__ P, float* __restrict__ attn) {
  __shared__ float Pt[4][32][68];   // per-wave slice, 2 tiles of 16 rows
  int wg = blockIdx.x;              // 1536 = 8 xcd * 192
  int xcd = wg & 7, rr = wg >> 3;
  int qt = rr % 6, bh = xcd + 8 * (rr / 6);
  int tid = threadIdx.x, w = tid >> 6, lane = tid & 63;
  int lr = lane & 15, lg = lane >> 4;
  int qw = qt * 128 + w * 32;
  float f = (fmaxf(scal[5], 1e-8f) / 127.f) * (fmaxf(scal[6], 1e-8f) / 127.f) * cScale;
  float sv = fmaxf(scal[7], 1e-8f) / 127.f;
  float sp = fmaxf(1.0f / scal[8], 1e-8f) / 32767.f;
  float mr[2][4], cr[2][4];
#pragma unroll
  for (int ti = 0; ti < 2; ++ti)
#pragma unroll
    for (int r = 0; r < 4; ++r) {
      int qq = qw + ti * 16 + lg * 4 + r;
      bool v = qq < cS;
      mr[ti][r] = v ? rowM[(long)bh * cS + qq] : 0.f;
      float Z = v ? rowZ[(long)bh * cS + qq] : 1.f;
      cr[ti][r] = v ? 1.0f / (Z * sp) : 0.f;
    }
  bf16x8 qa[2][3];
#pragma unroll
  for (int ti = 0; ti < 2; ++ti) {
    const ushort_t* Qp = qb + ((long)bh * cSP + qw + ti * 16 + lr) * cDP96 + lg * 8;
    qa[ti][0] = *(const bf16x8*)(Qp);
    qa[ti][1] = *(const bf16x8*)(Qp + 32);
    qa[ti][2] = *(const bf16x8*)(Qp + 64);
  }

  const ushort_t* Kbase = kb + (long)bh * cSP * cDP96 + (long)lr * cDP96 + lg * 8;
  f32x4 accPV[2][5] = {};
  for (int c = 0; c < 12; ++c) {
    int k0 = c * 64;
    // ---- QK: K frags scoped to this phase (dead before PV -> lower VGPR)
    {
      bf16x8 kf[12];
#pragma unroll
      for (int t = 0; t < 4; ++t)
#pragma unroll
        for (int s = 0; s < 3; ++s)
          kf[t * 3 + s] = *(const bf16x8*)(Kbase + (long)(k0 + t * 16) * cDP96 + s * 32);
#pragma unroll
      for (int t = 0; t < 4; ++t) {
        f32x4 a0 = {0.f, 0.f, 0.f, 0.f};
        f32x4 a1 = {0.f, 0.f, 0.f, 0.f};
        __builtin_amdgcn_s_setprio(1);
        a0 = MFMA16(qa[0][0], kf[t * 3 + 0], a0, 0, 0, 0);
        a1 = MFMA16(qa[1][0], kf[t * 3 + 0], a1, 0, 0, 0);
        a0 = MFMA16(qa[0][1], kf[t * 3 + 1], a0, 0, 0, 0);
        a1 = MFMA16(qa[1][1], kf[t * 3 + 1], a1, 0, 0, 0);
        a0 = MFMA16(qa[0][2], kf[t * 3 + 2], a0, 0, 0, 0);
        a1 = MFMA16(qa[1][2], kf[t * 3 + 2], a1, 0, 0, 0);
        __builtin_amdgcn_s_setprio(0);
        bool kval = (k0 + t * 16 + lr) < cS;
#pragma unroll
        for (int r = 0; r < 4; ++r) {
          float e0 = __expf(a0[r] * f - mr[0][r]);
          float n0 = fminf(rintf(e0 * cr[0][r]), 32767.f);
          Pt[w][lg * 4 + r][t * 16 + lr] = kval ? n0 * sp : 0.f;
          float e1 = __expf(a1[r] * f - mr[1][r]);
          float n1 = fminf(rintf(e1 * cr[1][r]), 32767.f);
          Pt[w][16 + lg * 4 + r][t * 16 + lr] = kval ? n1 * sp : 0.f;
        }
      }
    }
    __builtin_amdgcn_wave_barrier();
    // ---- P write: nontemporal (never re-read on device)
    if (k0 + 64 <= cS) {
#pragma unroll
      for (int it = 0; it < 8; ++it) {
        int e = it * 64 + lane;
        int row = e >> 4, c4 = e & 15;
        int q = qw + row;
        if (q < cS) {
          f32x4 pv4 = *(const f32x4*)&Pt[w][row][c4 * 4];
          __builtin_nontemporal_store(pv4, (f32x4*)&P[((long)bh * cS + q) * cS + k0 + c4 * 4]);
        }
      }
    } else {
      int ncol = cS - k0;
#pragma unroll 4
      for (int j = 0; j < 32; ++j) {
        int q = qw + j;
        if (q < cS && lane < ncol)
          __builtin_nontemporal_store(Pt[w][j][lane], &P[((long)bh * cS + q) * cS + k0 + lane]);
      }
    }
    __builtin_amdgcn_wave_barrier();
    // ---- PV: A = P rows (Dekker hi/lo bf16), B = vT (per-ks V frags)
#pragma unroll
    for (int ks = 0; ks < 2; ++ks) {
      bf16x8 vf5[5];
#pragma unroll
      for (int dt = 0; dt < 5; ++dt)
        vf5[dt] = *(const bf16x8*)(vT + ((long)bh * cVD + dt * 16 + lr) * cSP + k0 + ks * 32 + lg * 8);
#pragma unroll
      for (int ti = 0; ti < 2; ++ti) {
        const float* prow = &Pt[w][ti * 16 + lr][ks * 32 + lg * 8];
        bf16x8 hif, lof;
#pragma unroll
        for (int i = 0; i < 8; ++i) {
          float p = prow[i];
          unsigned short hu = f2bf(p);
          float lo = p - bf2f(hu);
          hif[i] = (short)hu;
          lof[i] = (short)f2bf(lo);
        }
        __builtin_amdgcn_s_setprio(1);
#pragma unroll
        for (int dt = 0; dt < 5; ++dt) {
          accPV[ti][dt] = MFMA16(hif, vf5[dt], accPV[ti][dt], 0, 0, 0);
          accPV[ti][dt] = MFMA16(lof, vf5[dt], accPV[ti][dt], 0, 0, 0);
        }
        __builtin_amdgcn_s_setprio(0);
      }
    }
    __builtin_amdgcn_wave_barrier();
  }
  int b = bh >> 4, h = bh & 15;
  float amx = 0.f;
#pragma unroll
  for (int ti = 0; ti < 2; ++ti)
#pragma unroll
    for (int dt = 0; dt < 5; ++dt)
#pragma unroll
      for (int r = 0; r < 4; ++r) {
        int q = qw + ti * 16 + lg * 4 + r, d = dt * 16 + lr;
        if (q < cS && d < cD) {
          float av = accPV[ti][dt][r] * sv;
          attn[((long)(b * cS + q)) * cE + h * cD + d] = av;
          amx = fmaxf(amx, fabsf(av));
        }
      }
  for (int o = 32; o; o >>= 1) amx = fmaxf(amx, __shfl_xor(amx, o));
  if (lane == 0) atomicMax((unsigned int*)(scal + 9), __float_as_uint(amx));
}

// ---------------------------------------------------------------------------
extern "C" void kernel_launch(void* const* d_in, const int* in_sizes, int n_in,
                              void* d_out, int out_size, void* d_ws, size_t ws_size,
                              hipStream_t stream) {
  (void)in_sizes; (void)n_in; (void)out_size;
  if (ws_size < WS_TOTAL) return;

  const float* hs = (const float*)d_in[0];
  const float* wq = (const float*)d_in[1];
  const float* bq = (const float*)d_in[2];
  const float* wk = (const float*)d_in[3];
  const float* bk = (const float*)d_in[4];
  const float* wv = (const float*)d_in[5];
  const float* bv = (const float*)d_in[6];
  const float* wo = (const float*)d_in[7];
  const float* bo = (const float*)d_in[8];

  char* ws = (char*)d_ws;
  float* scal = (float*)(ws + B_SCAL);
  char* W2O  = ws + B_W2O;
  char* W2Q  = ws + B_W2Q;    // W2K, W2V follow contiguously
  char* A2   = ws + B_A2;
  ushort_t* vT = (ushort_t*)(ws + B_VT);
  ushort_t* qb = (ushort_t*)(ws + B_QB);
  ushort_t* kb = (ushort_t*)(ws + B_KB);
  float* rowM = (float*)(ws + B_ROWM);
  float* rowZ = (float*)(ws + B_ROWZ);

  float* outb = (float*)d_out;           // attn_output region (also attn scratch)
  float* Pout = outb + cQKV;             // attn_weights region (also Rq/Rk/Rv scratch)
  float* Rq = Pout;
  float* Rk = Pout + cQKV;
  float* Rv = Pout + 2 * cQKV;

  init_k<<<1, 64, 0, stream>>>(scal);

  // absmax of all raw inputs (one launch)
  absmax5_k<<<dim3(512, 5), 256, 0, stream>>>((const float4*)hs, (const float4*)wq, (const float4*)wk,
                                              (const float4*)wv, (const float4*)wo, (unsigned int*)scal);

  // pack weights (one launch) + hidden to i8 hi/lo planes
  packW4_k<<<dim3(324, 4), 256, 0, stream>>>(wq, wk, wv, wo, scal, W2Q, W2O);
  pack8_k<<<3312, 256, 0, stream>>>(hs, scal + 0, A2, cM);

  // merged Q/K/V projection (fused absmax -> slots 5,6,7), XCD-chunked 1D grid
  mgemm_k<0><<<2484, 256, 0, stream>>>(A2, W2Q, bq, bk, bv, Rq, scal);

  // merged q/k/v conversions for attention (one launch)
  qkv8_k<<<dim3(4096, 3), 256, 0, stream>>>(Rq, Rk, Rv, qb, kb, vT, scal);

  // attention (XCD-swizzled 1D grids)
  qk_statsA<<<768, 256, 0, stream>>>(qb, kb, scal, rowM, rowZ, (unsigned int*)(scal + 8));
  qk_pv<<<1536, 256, 0, stream>>>(qb, kb, vT, rowM, rowZ, scal, Pout, outb);

  // O projection: pack attn (slot 9 from qk_pv), GEMM -> final attn_output
  pack8_k<<<3312, 256, 0, stream>>>(outb, scal + 9, A2, cM);
  mgemm_k<1><<<828, 256, 0, stream>>>(A2, W2O, bo, bo, bo, outb, scal);
}

// Round 13
// 751.992 us; speedup vs baseline: 1.0852x; 1.0044x over previous
//
#include <hip/hip_runtime.h>
#include <cstdint>
#include <cstddef>

// ---------------------------------------------------------------------------
// SiglipAttention fake-quant.  B=16 S=729 E=1152 H=16 D=72.
// Outputs fp32: attn_output (B,S,E) then attn_weights (B,H,S,S).
// Round 13: mgemm counted-wait pipeline (T4): vmcnt(0) now waits on loads
//           issued a full K-step earlier, not just-issued ones.  Two-barrier
//           schedule, race-audited.  Everything else identical to round 12.
// ---------------------------------------------------------------------------

typedef unsigned short ushort_t;

constexpr int   cB = 16, cS = 729, cE = 1152, cH = 16, cD = 72;
constexpr int   cM = cB * cS;                    // 11664
constexpr long  cQKV  = (long)cM * cE;           // 13,436,928
constexpr long  cWN   = (long)cE * cE;           // 1,327,104
constexpr float cScale = 0.11785113019775792f;   // 72^-0.5
constexpr int   cSP = 768;                       // padded S rows for qb/kb
constexpr int   cDP96 = 96;                      // padded D for MFMA K
constexpr int   cVD = 80;                        // vT d-rows (72 used + 8 pad)
constexpr int   cMF = 11776;                     // padded M (92 tiles of 128)
constexpr int   cRB = 2304;                      // i8 row bytes: [h 1152 | l 1152]

// ---- workspace byte offsets (total ~147 MB <= proven 243.7 MB) -------------
constexpr size_t B_SCAL = 0;                                    // 16 f32
constexpr size_t SZ_W2  = (size_t)cE * cRB;                     // 2,654,208
constexpr size_t B_W2O  = 256;
constexpr size_t B_W2Q  = B_W2O + SZ_W2;                        // W2Q,K,V contiguous
constexpr size_t B_A2   = B_W2Q + 3 * SZ_W2;
constexpr size_t SZ_A2  = (size_t)cMF * cRB;                    // 27,131,904
constexpr size_t B_VT   = B_A2 + SZ_A2;
constexpr size_t SZ_VT  = (size_t)256 * cVD * cSP * 2;          // 31,457,280
constexpr size_t B_QB   = B_VT + SZ_VT;
constexpr size_t SZ_QB  = (size_t)256 * cSP * cDP96 * 2;        // 37,748,736
constexpr size_t B_KB   = B_QB + SZ_QB;
constexpr size_t B_ROWM = B_KB + SZ_QB;
constexpr size_t SZ_ROW = (size_t)256 * cS * 4;                 // 746,496
constexpr size_t B_ROWZ = B_ROWM + SZ_ROW;
constexpr size_t WS_TOTAL = B_ROWZ + SZ_ROW;
static_assert(WS_TOTAL <= 243689728, "stay under proven ws size");

// scalar slots: 0 hid,1 wq,2 wk,3 wv,4 wo,5 q,6 k,7 v,8 minZ,9 attn

typedef __attribute__((ext_vector_type(8))) short bf16x8;
typedef __attribute__((ext_vector_type(4))) float f32x4;
typedef __attribute__((ext_vector_type(4))) int   i32x4;
#define MFMA16 __builtin_amdgcn_mfma_f32_16x16x32_bf16
#define MFMAI8 __builtin_amdgcn_mfma_i32_16x16x64_i8

__device__ __forceinline__ unsigned short f2bf(float f) {
  unsigned u = __float_as_uint(f);
  return (unsigned short)((u + 0x7fffu + ((u >> 16) & 1u)) >> 16);   // RNE
}
__device__ __forceinline__ float bf2f(unsigned short h) {
  return __uint_as_float(((unsigned)h) << 16);
}
__device__ __forceinline__ void gload16(const void* g, void* l) {
  __builtin_amdgcn_global_load_lds((const __attribute__((address_space(1))) unsigned int*)g,
                                   (__attribute__((address_space(3))) unsigned int*)l, 16, 0, 0);
}

// ---------------------------------------------------------------------------
__global__ void init_k(float* sc) {
  int t = threadIdx.x;
  if (t < 16) sc[t] = (t == 8) ? __uint_as_float(0x7f800000u) : 0.0f;
}

// consolidated absmax over 5 tensors: blockIdx.y selects tensor -> scal[y]
__global__ __launch_bounds__(256) void absmax5_k(const float4* __restrict__ x0, const float4* __restrict__ x1,
                                                 const float4* __restrict__ x2, const float4* __restrict__ x3,
                                                 const float4* __restrict__ x4, unsigned int* __restrict__ scal) {
  int t = blockIdx.y;
  const float4* x = (t == 0) ? x0 : (t == 1) ? x1 : (t == 2) ? x2 : (t == 3) ? x3 : x4;
  long n4 = (t == 0) ? cQKV / 4 : cWN / 4;
  float m = 0.f;
  long i = (long)blockIdx.x * blockDim.x + threadIdx.x;
  long str = (long)gridDim.x * blockDim.x;
  for (; i < n4; i += str) {
    float4 v = x[i];
    m = fmaxf(m, fmaxf(fmaxf(fabsf(v.x), fabsf(v.y)), fmaxf(fabsf(v.z), fabsf(v.w))));
  }
  for (int o = 32; o; o >>= 1) m = fmaxf(m, __shfl_xor(m, o));
  __shared__ float red[4];
  int lane = threadIdx.x & 63, w = threadIdx.x >> 6;
  if (!lane) red[w] = m;
  __syncthreads();
  if (threadIdx.x == 0) {
    m = fmaxf(fmaxf(red[0], red[1]), fmaxf(red[2], red[3]));
    atomicMax(&scal[t], __float_as_uint(m));
  }
}

// ---------------------------------------------------------------------------
// fq16 -> integer n -> hi/lo i8 planes: n = 256*a + b (exact except clamp tail)
__global__ __launch_bounds__(256) void pack8_k(const float* __restrict__ src, const float* __restrict__ slot,
                                               char* __restrict__ dst, int nsrc) {
  float s = fmaxf(*slot, 1e-8f) / 32767.f;
  int i = blockIdx.x * 256 + threadIdx.x;
  int r = i / 72, c16 = i - r * 72;
  int m = (r < nsrc) ? r : nsrc - 1;
  const float4* p = (const float4*)(src + (long)m * cE + c16 * 16);
  float4 v[4] = {p[0], p[1], p[2], p[3]};
  const float* xv = (const float*)v;
  unsigned char hb[16] __attribute__((aligned(16)));
  unsigned char lb[16] __attribute__((aligned(16)));
#pragma unroll
  for (int j = 0; j < 16; ++j) {
    float t = rintf(xv[j] / s);
    t = fminf(fmaxf(t, -32767.f), 32767.f);
    float af = floorf(t * 0.00390625f + 0.5f);   // round-half-up to hi byte
    af = fminf(af, 127.f);
    float bf = t - 256.f * af;
    bf = fminf(fmaxf(bf, -128.f), 127.f);
    hb[j] = (unsigned char)((int)af & 0xff);
    lb[j] = (unsigned char)((int)bf & 0xff);
  }
  char* d = dst + (long)r * cRB + c16 * 16;
  *(uint4*)d = *(const uint4*)hb;
  *(uint4*)(d + 1152) = *(const uint4*)lb;
}

// consolidated weight pack: blockIdx.y = z (0 wq,1 wk,2 wv,3 wo)
__global__ __launch_bounds__(256) void packW4_k(const float* __restrict__ w0, const float* __restrict__ w1,
                                                const float* __restrict__ w2, const float* __restrict__ w3,
                                                const float* __restrict__ scal,
                                                char* __restrict__ W2Q, char* __restrict__ W2O) {
  int z = blockIdx.y;
  const float* src = (z == 0) ? w0 : (z == 1) ? w1 : (z == 2) ? w2 : w3;
  char* dst = (z < 3) ? (W2Q + (size_t)z * SZ_W2) : W2O;
  float s = fmaxf(scal[1 + z], 1e-8f) / 32767.f;
  int i = blockIdx.x * 256 + threadIdx.x;
  int r = i / 72, c16 = i - r * 72;
  const float4* p = (const float4*)(src + (long)r * cE + c16 * 16);
  float4 v[4] = {p[0], p[1], p[2], p[3]};
  const float* xv = (const float*)v;
  unsigned char hb[16] __attribute__((aligned(16)));
  unsigned char lb[16] __attribute__((aligned(16)));
#pragma unroll
  for (int j = 0; j < 16; ++j) {
    float t = rintf(xv[j] / s);
    t = fminf(fmaxf(t, -32767.f), 32767.f);
    float af = floorf(t * 0.00390625f + 0.5f);
    af = fminf(af, 127.f);
    float bf = t - 256.f * af;
    bf = fminf(fmaxf(bf, -128.f), 127.f);
    hb[j] = (unsigned char)((int)af & 0xff);
    lb[j] = (unsigned char)((int)bf & 0xff);
  }
  char* d = dst + (long)r * cRB + c16 * 16;
  *(uint4*)d = *(const uint4*)hb;
  *(uint4*)(d + 1152) = *(const uint4*)lb;
}

// ---------------------------------------------------------------------------
// int8 MFMA GEMM, counted-wait double-buffer pipeline (T4).
// Per K-step: vmcnt(0) [waits loads issued LAST step] -> barrier(a) ->
// stage(next) -> ds_read(cur) -> lgkmcnt(0) -> barrier(b) -> MFMA.
// barrier(a): publishes cur (each wave's vmcnt precedes arrival) AND makes
// cur^1 overwrite-safe (its readers passed lgkmcnt+barrier(b) last step).
// 1D grid, bijective XCD-chunk swizzle.  OM 0: nwg 2484; OM 1: nwg 828 + NT.
template <int OM>
__global__ __launch_bounds__(256, 2) void mgemm_k(const char* __restrict__ A2,
                                                  const char* __restrict__ W2base,
                                                  const float* __restrict__ b0, const float* __restrict__ b1,
                                                  const float* __restrict__ b2,
                                                  float* __restrict__ outbase, float* __restrict__ scal) {
  __shared__ char L[2][32768];
  int bsw = blockIdx.x;
  int c8 = bsw & 7, j8 = bsw >> 3;
  int Lid;
  if (OM == 0) Lid = (c8 < 4 ? c8 * 311 : 1244 + (c8 - 4) * 310) + j8;   // nwg 2484
  else         Lid = (c8 < 4 ? c8 * 104 : 416  + (c8 - 4) * 103) + j8;   // nwg 828
  int z   = (OM == 0) ? Lid / 828 : 0;
  int rem = (OM == 0) ? Lid - z * 828 : Lid;
  int yt = rem / 9, xt = rem - yt * 9;

  const char* W2 = W2base + (size_t)z * cE * cRB;
  const float* bias = (z == 0) ? b0 : (z == 1) ? b1 : b2;
  float* out = outbase + (long)z * cQKV;
  float sA = fmaxf(scal[OM == 0 ? 0 : 9], 1e-8f) / 32767.f;
  float sW = fmaxf(scal[OM == 0 ? 1 + z : 4], 1e-8f) / 32767.f;
  float sc = sA * sW;

  int tid = threadIdx.x, w = tid >> 6, lane = tid & 63;
  int lr = lane & 15, kc = lane >> 4;
  int mt = yt * 128, nt = xt * 128;
  int wr = (w >> 1) * 64, wc = (w & 1) * 64;

  bool isA = (w < 2);
  const char* mat = isA ? (A2 + (long)mt * cRB) : (W2 + (long)nt * cRB);
  const char* src[8];
  int ldo[8];
#pragma unroll
  for (int j = 0; j < 8; ++j) {
    int seg = (w & 1) * 8 + j;
    int o = seg * 1024 + lane * 16;
    int row = o >> 7, chs = (o >> 4) & 7, orig = chs ^ (row & 7);
    src[j] = mat + (long)row * cRB + (orig >> 2) * 1152 + (orig & 3) * 16;
    ldo[j] = (isA ? 0 : 16384) + seg * 1024;
  }

  int aoffH[4], aoffL[4], boffH[4], boffL[4];
#pragma unroll
  for (int i = 0; i < 4; ++i) {
    int ra = wr + i * 16 + lr;
    aoffH[i] = ra * 128 + ((kc ^ (ra & 7)) << 4);
    aoffL[i] = ra * 128 + (((kc + 4) ^ (ra & 7)) << 4);
    int rb = wc + i * 16 + lr;
    boffH[i] = 16384 + rb * 128 + ((kc ^ (rb & 7)) << 4);
    boffL[i] = 16384 + rb * 128 + (((kc + 4) ^ (rb & 7)) << 4);
  }

  auto stage = [&](int buf, int kk) {
#pragma unroll
    for (int j = 0; j < 8; ++j)
      gload16(src[j] + (long)kk * 64, &L[buf][ldo[j]]);
  };

  i32x4 P1[4][4] = {};
  i32x4 Pm[4][4] = {};
  stage(0, 0);
  int cur = 0;
  for (int kk = 0; kk < 18; ++kk) {
    // wait for buf `cur`'s 8 loads (issued one full K-step ago; ~free)
    asm volatile("s_waitcnt vmcnt(0)" ::: "memory");
    __builtin_amdgcn_s_barrier();            // (a) cur published; cur^1 safe
    if (kk < 17) stage(cur ^ 1, kk + 1);     // in flight across next barrier
    i32x4 ah[4], al[4], whf[4], wlf[4];
#pragma unroll
    for (int i = 0; i < 4; ++i) {
      ah[i]  = *(const i32x4*)&L[cur][aoffH[i]];
      al[i]  = *(const i32x4*)&L[cur][aoffL[i]];
      whf[i] = *(const i32x4*)&L[cur][boffH[i]];
      wlf[i] = *(const i32x4*)&L[cur][boffL[i]];
    }
    asm volatile("s_waitcnt lgkmcnt(0)" ::: "memory");
    __builtin_amdgcn_s_barrier();            // (b) all waves done reading cur
#pragma unroll
    for (int i = 0; i < 4; ++i)
#pragma unroll
      for (int j = 0; j < 4; ++j) {
        P1[i][j] = MFMAI8(ah[i], whf[j], P1[i][j], 0, 0, 0);
        Pm[i][j] = MFMAI8(ah[i], wlf[j], Pm[i][j], 0, 0, 0);
        Pm[i][j] = MFMAI8(al[i], whf[j], Pm[i][j], 0, 0, 0);
      }
    cur ^= 1;
  }

  float amx = 0.f;
#pragma unroll
  for (int i = 0; i < 4; ++i) {
#pragma unroll
    for (int r = 0; r < 4; ++r) {
      int m = mt + wr + i * 16 + kc * 4 + r;
      if (m >= cM) continue;
      int b = m / cS, s = m - b * cS;
#pragma unroll
      for (int j = 0; j < 4; ++j) {
        int n = nt + wc + j * 16 + lr;
        float val = 65536.f * (float)P1[i][j][r] + 256.f * (float)Pm[i][j][r];
        float cv = sc * val + bias[n];
        if (OM == 1) {
          __builtin_nontemporal_store(cv, &out[(long)m * cE + n]);
        } else {
          int h = n / cD, d = n - h * cD;
          out[((long)(b * cH + h) * cS + s) * cD + d] = cv;
          amx = fmaxf(amx, fabsf(cv));
        }
      }
    }
  }
  if (OM == 0) {
    for (int o = 32; o; o >>= 1) amx = fmaxf(amx, __shfl_xor(amx, o));
    if (lane == 0) atomicMax((unsigned int*)(scal + 5 + z), __float_as_uint(amx));
  }
}

// ---------------------------------------------------------------------------
// merged conversions: z=0 q -> qb, z=1 k -> kb (integer-bf16, (bh,768,96));
// z=2 v -> vT transposed (bh,80,768).
__global__ __launch_bounds__(256) void qkv8_k(const float* __restrict__ Rq, const float* __restrict__ Rk,
                                              const float* __restrict__ Rv,
                                              ushort_t* __restrict__ qb, ushort_t* __restrict__ kb,
                                              ushort_t* __restrict__ vT, const float* __restrict__ scal) {
  __shared__ float T[64][73];
  int z = blockIdx.y;
  if (z < 2) {
    const float* src = z ? Rk : Rq;
    ushort_t* dst = z ? kb : qb;
    float s8 = fmaxf(scal[5 + z], 1e-8f) / 127.f;
    long total2 = (long)256 * cSP * cDP96 / 2;
    long i = (long)blockIdx.x * blockDim.x + threadIdx.x;
    long str = (long)gridDim.x * blockDim.x;
    for (; i < total2; i += str) {
      long e = i * 2;
      int d = (int)(e % cDP96);
      long rem = e / cDP96;
      int s = (int)(rem % cSP);
      int bh = (int)(rem / cSP);
      float v0 = 0.f, v1 = 0.f;
      if (s < cS && d < cD) {
        const float* p = src + ((long)bh * cS + s) * cD + d;
        v0 = p[0]; v1 = p[1];
      }
      float n0 = fminf(fmaxf(rintf(v0 / s8), -127.f), 127.f);
      float n1 = fminf(fmaxf(rintf(v1 / s8), -127.f), 127.f);
      ushort2 o; o.x = f2bf(n0); o.y = f2bf(n1);
      *(ushort2*)(dst + e) = o;
    }
  } else {
    int bx = blockIdx.x;
    if (bx >= 3072) return;             // 256 bh x 12 k-tiles
    int bh = bx / 12, k0 = (bx - (bx / 12) * 12) * 64;
    int tid = threadIdx.x;
    float s8 = fmaxf(scal[7], 1e-8f) / 127.f;
    for (int e = tid; e < 64 * 72; e += 256) {
      int r = e / 72, c = e - r * 72;
      T[r][c] = (k0 + r < cS) ? Rv[((long)bh * cS + k0 + r) * cD + c] : 0.f;
    }
    __syncthreads();
    for (int e = tid; e < 64 * 80; e += 256) {
      int d = e >> 6, kk = e & 63;
      float val = (d < cD && k0 + kk < cS) ? T[kk][d] : 0.f;
      float n = fminf(fmaxf(rintf(val / s8), -127.f), 127.f);
      vT[((long)bh * cVD + d) * cSP + k0 + kk] = f2bf(n);
    }
  }
}

// ---------------------------------------------------------------------------
// pass A: swapped mfma(K,Q) -> per-row m,Z; global min Z.  1D grid 768,
// XCD-swizzled.  64 q-rows per wave; setprio around MFMA cluster.
__global__ __launch_bounds__(256) void qk_statsA(const ushort_t* __restrict__ qb,
                                                 const ushort_t* __restrict__ kb,
                                                 const float* __restrict__ scal,
                                                 float* __restrict__ rowM, float* __restrict__ rowZ,
                                                 unsigned int* __restrict__ minZ) {
  int wg = blockIdx.x;                 // 768 = 8 xcd * 96
  int xcd = wg & 7, rr = wg >> 3;
  int qt = rr % 3, bh = xcd + 8 * (rr / 3);
  int w = threadIdx.x >> 6, lane = threadIdx.x & 63;
  int lr = lane & 15, lg = lane >> 4;
  int q0 = qt * 256 + w * 64;
  float f = (fmaxf(scal[5], 1e-8f) / 127.f) * (fmaxf(scal[6], 1e-8f) / 127.f) * cScale;
  bf16x8 qa[4][3];
#pragma unroll
  for (int ti = 0; ti < 4; ++ti) {
    const ushort_t* Qp = qb + ((long)bh * cSP + q0 + ti * 16 + lr) * cDP96 + lg * 8;
    qa[ti][0] = *(const bf16x8*)(Qp);
    qa[ti][1] = *(const bf16x8*)(Qp + 32);
    qa[ti][2] = *(const bf16x8*)(Qp + 64);
  }
  const ushort_t* Kp0 = kb + ((long)bh * cSP + lr) * cDP96 + lg * 8;
  float m[4] = {-INFINITY, -INFINITY, -INFINITY, -INFINITY};
  float z[4] = {0.f, 0.f, 0.f, 0.f};
  for (int k0 = 0; k0 < 736; k0 += 16) {
    const ushort_t* Kp = Kp0 + (long)k0 * cDP96;
    bf16x8 kA = *(const bf16x8*)(Kp);
    bf16x8 kB = *(const bf16x8*)(Kp + 32);
    bf16x8 kC = *(const bf16x8*)(Kp + 64);
    int kbase = k0 + lg * 4;
    bool v0 = kbase + 0 < cS, v1 = kbase + 1 < cS, v2 = kbase + 2 < cS, v3 = kbase + 3 < cS;
#pragma unroll
    for (int ti = 0; ti < 4; ++ti) {
      f32x4 acc = {0.f, 0.f, 0.f, 0.f};
      __builtin_amdgcn_s_setprio(1);
      acc = MFMA16(kA, qa[ti][0], acc, 0, 0, 0);
      acc = MFMA16(kB, qa[ti][1], acc, 0, 0, 0);
      acc = MFMA16(kC, qa[ti][2], acc, 0, 0, 0);
      __builtin_amdgcn_s_setprio(0);
      float l0 = v0 ? acc[0] * f : -INFINITY;
      float l1 = v1 ? acc[1] * f : -INFINITY;
      float l2 = v2 ? acc[2] * f : -INFINITY;
      float l3 = v3 ? acc[3] * f : -INFINITY;
      float tm = fmaxf(fmaxf(l0, l1), fmaxf(l2, l3));
      float mn = fmaxf(m[ti], tm);
      z[ti] = z[ti] * __expf(m[ti] - mn) + __expf(l0 - mn) + __expf(l1 - mn) + __expf(l2 - mn) + __expf(l3 - mn);
      m[ti] = mn;
    }
  }
  float zs = __uint_as_float(0x7f800000u);
#pragma unroll
  for (int ti = 0; ti < 4; ++ti) {
#pragma unroll
    for (int o = 16; o <= 32; o <<= 1) {
      float mo = __shfl_xor(m[ti], o);
      float zo = __shfl_xor(z[ti], o);
      float mn = fmaxf(m[ti], mo);
      z[ti] = z[ti] * __expf(m[ti] - mn) + zo * __expf(mo - mn);
      m[ti] = mn;
    }
    int q = q0 + ti * 16 + lr;
    if (lane < 16 && q < cS) {
      rowM[(long)bh * cS + q] = m[ti];
      rowZ[(long)bh * cS + q] = z[ti];
    }
    if (q < cS) zs = fminf(zs, z[ti]);
  }
#pragma unroll
  for (int o = 1; o < 16; o <<= 1) zs = fminf(zs, __shfl_xor(zs, o));
  if (lane == 0) atomicMin(minZ, __float_as_uint(zs));
}

// ---------------------------------------------------------------------------
// pass B fused, wave-independent, 32 q-rows per wave.  1D grid 1536,
// XCD-swizzled.  K frags chunk-scoped, V frags per-ks; setprio around MFMA.
__global__ __launch_bounds__(256) void qk_pv(const ushort_t* __restrict__ qb,
                                             const ushort_t* __restrict__ kb,
                                             const ushort_t* __restrict__ vT,
                                             const float* __restrict__ rowM, const float* __restrict__ rowZ,
                                             float* __restrict__ scal,
                                             float* __restrict__ P, float* __restrict__ attn) {
  __shared__ float Pt[4][32][68];   // per-wave slice, 2 tiles of 16 rows
  int wg = blockIdx.x;              // 1536 = 8 xcd * 192
  int xcd = wg & 7, rr = wg >> 3;
  int qt = rr % 6, bh = xcd + 8 * (rr / 6);
  int tid = threadIdx.x, w = tid >> 6, lane = tid & 63;
  int lr = lane & 15, lg = lane >> 4;
  int qw = qt * 128 + w * 32;
  float f = (fmaxf(scal[5], 1e-8f) / 127.f) * (fmaxf(scal[6], 1e-8f) / 127.f) * cScale;
  float sv = fmaxf(scal[7], 1e-8f) / 127.f;
  float sp = fmaxf(1.0f / scal[8], 1e-8f) / 32767.f;
  float mr[2][4], cr[2][4];
#pragma unroll
  for (int ti = 0; ti < 2; ++ti)
#pragma unroll
    for (int r = 0; r < 4; ++r) {
      int qq = qw + ti * 16 + lg * 4 + r;
      bool v = qq < cS;
      mr[ti][r] = v ? rowM[(long)bh * cS + qq] : 0.f;
      float Z = v ? rowZ[(long)bh * cS + qq] : 1.f;
      cr[ti][r] = v ? 1.0f / (Z * sp) : 0.f;
    }
  bf16x8 qa[2][3];
#pragma unroll
  for (int ti = 0; ti < 2; ++ti) {
    const ushort_t* Qp = qb + ((long)bh * cSP + qw + ti * 16 + lr) * cDP96 + lg * 8;
    qa[ti][0] = *(const bf16x8*)(Qp);
    qa[ti][1] = *(const bf16x8*)(Qp + 32);
    qa[ti][2] = *(const bf16x8*)(Qp + 64);
  }

  const ushort_t* Kbase = kb + (long)bh * cSP * cDP96 + (long)lr * cDP96 + lg * 8;
  f32x4 accPV[2][5] = {};
  for (int c = 0; c < 12; ++c) {
    int k0 = c * 64;
    // ---- QK: K frags scoped to this phase (dead before PV -> lower VGPR)
    {
      bf16x8 kf[12];
#pragma unroll
      for (int t = 0; t < 4; ++t)
#pragma unroll
        for (int s = 0; s < 3; ++s)
          kf[t * 3 + s] = *(const bf16x8*)(Kbase + (long)(k0 + t * 16) * cDP96 + s * 32);
#pragma unroll
      for (int t = 0; t < 4; ++t) {
        f32x4 a0 = {0.f, 0.f, 0.f, 0.f};
        f32x4 a1 = {0.f, 0.f, 0.f, 0.f};
        __builtin_amdgcn_s_setprio(1);
        a0 = MFMA16(qa[0][0], kf[t * 3 + 0], a0, 0, 0, 0);
        a1 = MFMA16(qa[1][0], kf[t * 3 + 0], a1, 0, 0, 0);
        a0 = MFMA16(qa[0][1], kf[t * 3 + 1], a0, 0, 0, 0);
        a1 = MFMA16(qa[1][1], kf[t * 3 + 1], a1, 0, 0, 0);
        a0 = MFMA16(qa[0][2], kf[t * 3 + 2], a0, 0, 0, 0);
        a1 = MFMA16(qa[1][2], kf[t * 3 + 2], a1, 0, 0, 0);
        __builtin_amdgcn_s_setprio(0);
        bool kval = (k0 + t * 16 + lr) < cS;
#pragma unroll
        for (int r = 0; r < 4; ++r) {
          float e0 = __expf(a0[r] * f - mr[0][r]);
          float n0 = fminf(rintf(e0 * cr[0][r]), 32767.f);
          Pt[w][lg * 4 + r][t * 16 + lr] = kval ? n0 * sp : 0.f;
          float e1 = __expf(a1[r] * f - mr[1][r]);
          float n1 = fminf(rintf(e1 * cr[1][r]), 32767.f);
          Pt[w][16 + lg * 4 + r][t * 16 + lr] = kval ? n1 * sp : 0.f;
        }
      }
    }
    __builtin_amdgcn_wave_barrier();
    // ---- P write: nontemporal (never re-read on device)
    if (k0 + 64 <= cS) {
#pragma unroll
      for (int it = 0; it < 8; ++it) {
        int e = it * 64 + lane;
        int row = e >> 4, c4 = e & 15;
        int q = qw + row;
        if (q < cS) {
          f32x4 pv4 = *(const f32x4*)&Pt[w][row][c4 * 4];
          __builtin_nontemporal_store(pv4, (f32x4*)&P[((long)bh * cS + q) * cS + k0 + c4 * 4]);
        }
      }
    } else {
      int ncol = cS - k0;
#pragma unroll 4
      for (int j = 0; j < 32; ++j) {
        int q = qw + j;
        if (q < cS && lane < ncol)
          __builtin_nontemporal_store(Pt[w][j][lane], &P[((long)bh * cS + q) * cS + k0 + lane]);
      }
    }
    __builtin_amdgcn_wave_barrier();
    // ---- PV: A = P rows (Dekker hi/lo bf16), B = vT (per-ks V frags)
#pragma unroll
    for (int ks = 0; ks < 2; ++ks) {
      bf16x8 vf5[5];
#pragma unroll
      for (int dt = 0; dt < 5; ++dt)
        vf5[dt] = *(const bf16x8*)(vT + ((long)bh * cVD + dt * 16 + lr) * cSP + k0 + ks * 32 + lg * 8);
#pragma unroll
      for (int ti = 0; ti < 2; ++ti) {
        const float* prow = &Pt[w][ti * 16 + lr][ks * 32 + lg * 8];
        bf16x8 hif, lof;
#pragma unroll
        for (int i = 0; i < 8; ++i) {
          float p = prow[i];
          unsigned short hu = f2bf(p);
          float lo = p - bf2f(hu);
          hif[i] = (short)hu;
          lof[i] = (short)f2bf(lo);
        }
        __builtin_amdgcn_s_setprio(1);
#pragma unroll
        for (int dt = 0; dt < 5; ++dt) {
          accPV[ti][dt] = MFMA16(hif, vf5[dt], accPV[ti][dt], 0, 0, 0);
          accPV[ti][dt] = MFMA16(lof, vf5[dt], accPV[ti][dt], 0, 0, 0);
        }
        __builtin_amdgcn_s_setprio(0);
      }
    }
    __builtin_amdgcn_wave_barrier();
  }
  int b = bh >> 4, h = bh & 15;
  float amx = 0.f;
#pragma unroll
  for (int ti = 0; ti < 2; ++ti)
#pragma unroll
    for (int dt = 0; dt < 5; ++dt)
#pragma unroll
      for (int r = 0; r < 4; ++r) {
        int q = qw + ti * 16 + lg * 4 + r, d = dt * 16 + lr;
        if (q < cS && d < cD) {
          float av = accPV[ti][dt][r] * sv;
          attn[((long)(b * cS + q)) * cE + h * cD + d] = av;
          amx = fmaxf(amx, fabsf(av));
        }
      }
  for (int o = 32; o; o >>= 1) amx = fmaxf(amx, __shfl_xor(amx, o));
  if (lane == 0) atomicMax((unsigned int*)(scal + 9), __float_as_uint(amx));
}

// ---------------------------------------------------------------------------
extern "C" void kernel_launch(void* const* d_in, const int* in_sizes, int n_in,
                              void* d_out, int out_size, void* d_ws, size_t ws_size,
                              hipStream_t stream) {
  (void)in_sizes; (void)n_in; (void)out_size;
  if (ws_size < WS_TOTAL) return;

  const float* hs = (const float*)d_in[0];
  const float* wq = (const float*)d_in[1];
  const float* bq = (const float*)d_in[2];
  const float* wk = (const float*)d_in[3];
  const float* bk = (const float*)d_in[4];
  const float* wv = (const float*)d_in[5];
  const float* bv = (const float*)d_in[6];
  const float* wo = (const float*)d_in[7];
  const float* bo = (const float*)d_in[8];

  char* ws = (char*)d_ws;
  float* scal = (float*)(ws + B_SCAL);
  char* W2O  = ws + B_W2O;
  char* W2Q  = ws + B_W2Q;    // W2K, W2V follow contiguously
  char* A2   = ws + B_A2;
  ushort_t* vT = (ushort_t*)(ws + B_VT);
  ushort_t* qb = (ushort_t*)(ws + B_QB);
  ushort_t* kb = (ushort_t*)(ws + B_KB);
  float* rowM = (float*)(ws + B_ROWM);
  float* rowZ = (float*)(ws + B_ROWZ);

  float* outb = (float*)d_out;           // attn_output region (also attn scratch)
  float* Pout = outb + cQKV;             // attn_weights region (also Rq/Rk/Rv scratch)
  float* Rq = Pout;
  float* Rk = Pout + cQKV;
  float* Rv = Pout + 2 * cQKV;

  init_k<<<1, 64, 0, stream>>>(scal);

  // absmax of all raw inputs (one launch)
  absmax5_k<<<dim3(512, 5), 256, 0, stream>>>((const float4*)hs, (const float4*)wq, (const float4*)wk,
                                              (const float4*)wv, (const float4*)wo, (unsigned int*)scal);

  // pack weights (one launch) + hidden to i8 hi/lo planes
  packW4_k<<<dim3(324, 4), 256, 0, stream>>>(wq, wk, wv, wo, scal, W2Q, W2O);
  pack8_k<<<3312, 256, 0, stream>>>(hs, scal + 0, A2, cM);

  // merged Q/K/V projection (fused absmax -> slots 5,6,7), XCD-chunked 1D grid
  mgemm_k<0><<<2484, 256, 0, stream>>>(A2, W2Q, bq, bk, bv, Rq, scal);

  // merged q/k/v conversions for attention (one launch)
  qkv8_k<<<dim3(4096, 3), 256, 0, stream>>>(Rq, Rk, Rv, qb, kb, vT, scal);

  // attention (XCD-swizzled 1D grids)
  qk_statsA<<<768, 256, 0, stream>>>(qb, kb, scal, rowM, rowZ, (unsigned int*)(scal + 8));
  qk_pv<<<1536, 256, 0, stream>>>(qb, kb, vT, rowM, rowZ, scal, Pout, outb);

  // O projection: pack attn (slot 9 from qk_pv), GEMM -> final attn_output
  pack8_k<<<3312, 256, 0, stream>>>(outb, scal + 9, A2, cM);
  mgemm_k<1><<<828, 256, 0, stream>>>(A2, W2O, bo, bo, bo, outb, scal);
}